// Round 1
// baseline (825.230 us; speedup 1.0000x reference)
//
#include <hip/hip_runtime.h>
#include <hip/hip_cooperative_groups.h>

namespace cg = cooperative_groups;

#define DEVI static __device__ __forceinline__

constexpr int NT_ = 256;
constexpr int B_ = 256, HW_ = 1024, IN_ = 512, HID_ = 1024, H3_ = 3072;
constexpr int XD_ = 1537;        // feat(512) + mask(1024) + count(1)
constexpr int XDP_ = 1552;       // padded to multiple of 16 floats for float4 K-loads
constexpr int FLAT_ = 16384;     // 16 * 32 * 32, channel-major flatten

// workspace layout (float offsets)
constexpr int SZ_C2 = B_ * FLAT_;        // conv2 relu output, 4,194,304
constexpr int SZ_WIHP = H3_ * XDP_;      // padded wih, 4,767,744
constexpr int SZ_XBUF = B_ * XDP_;       // x = [feat|mask|count|pad], 397,312
constexpr int SZ_H = B_ * HID_;          // 262,144
constexpr int SZ_G = B_ * H3_;           // 786,432
constexpr int OFF_C2 = 0;
constexpr int OFF_WIHP = OFF_C2 + SZ_C2;
constexpr int OFF_XBUF = OFF_WIHP + SZ_WIHP;
constexpr int OFF_H = OFF_XBUF + SZ_XBUF;
constexpr int OFF_GI = OFF_H + SZ_H;
constexpr int OFF_GH = OFF_GI + SZ_G;
constexpr int OFF_DONE = OFF_GH + SZ_G;  // int flag
// lin split-K partials (8 * 256 * 512 = 1,048,576) alias OFF_GI..OFF_GH+SZ_G (1,572,864)

struct Params {
  const float* grid;
  const float* c1w; const float* c1b;
  const float* c2w; const float* c2b;
  const float* linw; const float* linb;
  const float* wih; const float* whh;
  const float* bih; const float* bhh;
  const float* ww;  const float* wb;
  const float* incw; const float* incb;
  const float* termw; const float* termb;
  const int* max_steps;
  float* out;   // [0:256) count, [256:262400) mask row-major [256][1024]
  float* ws;
};

DEVI float sigm(float x) { return 1.f / (1.f + __expf(-x)); }
DEVI void ld4(float* d, const float* p) {
  float4 v = *(const float4*)p; d[0] = v.x; d[1] = v.y; d[2] = v.z; d[3] = v.w;
}
DEVI void st4(float* p, const float* s) {
  float4 v = {s[0], s[1], s[2], s[3]}; *(float4*)p = v;
}

// ---------------- conv front-end: one block per batch element ----------------
__global__ __launch_bounds__(NT_) void conv_kernel(Params p) {
  __shared__ float s_in[34 * 34];        // 1-halo padded input
  __shared__ float s_c1[8 * 34 * 34];    // 1-halo padded conv1 relu
  const int b = blockIdx.x;
  const int tid = threadIdx.x;
  for (int i = tid; i < 34 * 34; i += NT_) s_in[i] = 0.f;
  for (int i = tid; i < 8 * 34 * 34; i += NT_) s_c1[i] = 0.f;
  __syncthreads();
  for (int i = tid; i < 1024; i += NT_) {
    int y = i >> 5, x = i & 31;
    s_in[(y + 1) * 34 + (x + 1)] = p.grid[b * 1024 + i];
  }
  __syncthreads();
  // conv1: each thread computes 4 consecutive-x outputs for all 8 oc
  const int pos0 = tid * 4;
  const int y = pos0 >> 5, x0 = pos0 & 31;
  {
    float win[3][6];
    #pragma unroll
    for (int dy = 0; dy < 3; ++dy)
      #pragma unroll
      for (int c = 0; c < 6; ++c) win[dy][c] = s_in[(y + dy) * 34 + x0 + c];
    float acc[8][4];
    #pragma unroll
    for (int oc = 0; oc < 8; ++oc)
      #pragma unroll
      for (int i = 0; i < 4; ++i) acc[oc][i] = p.c1b[oc];
    #pragma unroll
    for (int oc = 0; oc < 8; ++oc)
      #pragma unroll
      for (int dy = 0; dy < 3; ++dy)
        #pragma unroll
        for (int dx = 0; dx < 3; ++dx) {
          float w = p.c1w[oc * 9 + dy * 3 + dx];   // uniform -> s_load
          #pragma unroll
          for (int i = 0; i < 4; ++i)
            acc[oc][i] = fmaf(w, win[dy][i + dx], acc[oc][i]);
        }
    #pragma unroll
    for (int oc = 0; oc < 8; ++oc)
      #pragma unroll
      for (int i = 0; i < 4; ++i)
        s_c1[oc * 1156 + (y + 1) * 34 + (x0 + i + 1)] = fmaxf(acc[oc][i], 0.f);
  }
  __syncthreads();
  // conv2: each thread 4 consecutive-x outputs, all 16 oc, ic-outer window reuse
  {
    float acc[16][4];
    #pragma unroll
    for (int oc = 0; oc < 16; ++oc)
      #pragma unroll
      for (int i = 0; i < 4; ++i) acc[oc][i] = p.c2b[oc];
    for (int ic = 0; ic < 8; ++ic) {
      float win[3][6];
      #pragma unroll
      for (int dy = 0; dy < 3; ++dy)
        #pragma unroll
        for (int c = 0; c < 6; ++c)
          win[dy][c] = s_c1[ic * 1156 + (y + dy) * 34 + x0 + c];
      #pragma unroll
      for (int oc = 0; oc < 16; ++oc)
        #pragma unroll
        for (int dy = 0; dy < 3; ++dy)
          #pragma unroll
          for (int dx = 0; dx < 3; ++dx) {
            float w = p.c2w[oc * 72 + ic * 9 + dy * 3 + dx];  // uniform -> s_load
            #pragma unroll
            for (int i = 0; i < 4; ++i)
              acc[oc][i] = fmaf(w, win[dy][i + dx], acc[oc][i]);
          }
    }
    float* dst = p.ws + OFF_C2 + b * FLAT_;
    #pragma unroll
    for (int oc = 0; oc < 16; ++oc) {
      float4 v = {fmaxf(acc[oc][0], 0.f), fmaxf(acc[oc][1], 0.f),
                  fmaxf(acc[oc][2], 0.f), fmaxf(acc[oc][3], 0.f)};
      *(float4*)(dst + oc * 1024 + pos0) = v;
    }
  }
}

// ---------------- generic f32 GEMM tile: C[m][n] = sum_k A[m][k]*Bw[n][k] ----
// BM x BN tile, KT=16, 256 threads, micro-tile (BM/16) x (BN/16) per thread.
template <int BM, int BN>
DEVI void gemm_tile(const float* __restrict__ A, int lda,
                    const float* __restrict__ Bw, int ldb, int K,
                    float* __restrict__ As, float* __restrict__ Bs,
                    float (&acc)[BM / 16][BN / 16]) {
  constexpr int TM = BM / 16, TN = BN / 16;
  const int tid = threadIdx.x;
  const int tx = tid & 15, ty = tid >> 4;
  const int lrow = tid >> 2;
  const int lk = (tid & 3) * 4;
  #pragma unroll
  for (int i = 0; i < TM; ++i)
    #pragma unroll
    for (int j = 0; j < TN; ++j) acc[i][j] = 0.f;
  const bool aload = (BM == 64) || (tid < 128);
  const bool bload = (BN == 64) || (tid < 128);
  for (int k0 = 0; k0 < K; k0 += 16) {
    float4 va = {0, 0, 0, 0}, vb = {0, 0, 0, 0};
    if (aload) va = *(const float4*)(A + lrow * lda + k0 + lk);
    if (bload) vb = *(const float4*)(Bw + lrow * ldb + k0 + lk);
    __syncthreads();
    if (aload) {
      As[(lk + 0) * BM + lrow] = va.x; As[(lk + 1) * BM + lrow] = va.y;
      As[(lk + 2) * BM + lrow] = va.z; As[(lk + 3) * BM + lrow] = va.w;
    }
    if (bload) {
      Bs[(lk + 0) * BN + lrow] = vb.x; Bs[(lk + 1) * BN + lrow] = vb.y;
      Bs[(lk + 2) * BN + lrow] = vb.z; Bs[(lk + 3) * BN + lrow] = vb.w;
    }
    __syncthreads();
    #pragma unroll
    for (int kk = 0; kk < 16; ++kk) {
      float a[TM], b[TN];
      if constexpr (TM == 4) ld4(a, As + kk * BM + ty * 4);
      else { float2 t = *(const float2*)(As + kk * BM + ty * 2); a[0] = t.x; a[1] = t.y; }
      if constexpr (TN == 4) ld4(b, Bs + kk * BN + tx * 4);
      else { float2 t = *(const float2*)(Bs + kk * BN + tx * 2); b[0] = t.x; b[1] = t.y; }
      #pragma unroll
      for (int i = 0; i < TM; ++i)
        #pragma unroll
        for (int j = 0; j < TN; ++j) acc[i][j] = fmaf(a[i], b[j], acc[i][j]);
    }
  }
}

// ---------------- cooperative main kernel ----------------
__global__ __launch_bounds__(NT_, 2) void main_kernel(Params p) {
  cg::grid_group gg = cg::this_grid();
  __shared__ float sA[16 * 64];
  __shared__ float sB[16 * 64];
  __shared__ float rsum[8];
  float* const ws = p.ws;
  float* const c2f = ws + OFF_C2;
  float* const wihp = ws + OFF_WIHP;
  float* const xbuf = ws + OFF_XBUF;
  float* const hbuf = ws + OFF_H;
  float* const gi = ws + OFF_GI;
  float* const gh = ws + OFF_GH;
  float* const part = gi;  // lin split-K partials alias gi/gh
  int* const done = (int*)(ws + OFF_DONE);
  const int tid = threadIdx.x;
  const int bid = blockIdx.x;
  const int nb = gridDim.x;
  const int gt = bid * NT_ + tid;
  const int gstride = nb * NT_;

  // ---- init: repack wih to padded stride; zero h, out(count+mask), x pad ----
  for (int i = gt; i < SZ_WIHP; i += gstride) {
    int n = i / XDP_, k = i - n * XDP_;
    wihp[i] = (k < XD_) ? p.wih[n * XD_ + k] : 0.f;
  }
  for (int i = gt; i < SZ_H; i += gstride) hbuf[i] = 0.f;
  for (int i = gt; i < B_ * (HW_ + 1); i += gstride) p.out[i] = 0.f;
  for (int i = gt; i < B_ * (XDP_ - IN_); i += gstride) {  // mask/count/pad cols
    int m = i / (XDP_ - IN_), c = i - m * (XDP_ - IN_);
    xbuf[m * XDP_ + IN_ + c] = 0.f;
  }
  // ---- linear: feat = conv2flat @ linw^T + linb, split-K 8 x (32x64 tiles) ----
  for (int job = bid; job < 512; job += nb) {
    int ks = job >> 6, t = job & 63;
    int mt = t >> 3, nt = t & 7;
    float acc[2][4];
    gemm_tile<32, 64>(c2f + mt * 32 * FLAT_ + ks * 2048, FLAT_,
                      p.linw + nt * 64 * FLAT_ + ks * 2048, FLAT_, 2048,
                      sA, sB, acc);
    const int tx = tid & 15, ty = tid >> 4;
    float* dst = part + ks * (B_ * IN_);
    #pragma unroll
    for (int i = 0; i < 2; ++i)
      st4(dst + (mt * 32 + ty * 2 + i) * IN_ + nt * 64 + tx * 4, acc[i]);
  }
  gg.sync();
  // ---- reduce split-K partials -> feat into xbuf cols [0,512) ----
  for (int i = gt; i < B_ * IN_; i += gstride) {
    int m = i >> 9, o = i & (IN_ - 1);
    float s = p.linb[o];
    #pragma unroll
    for (int ks = 0; ks < 8; ++ks) s += part[ks * (B_ * IN_) + i];
    xbuf[m * XDP_ + o] = s;
  }
  gg.sync();

  const int msteps = p.max_steps[0];
  const float incb0 = p.incb[0];
  const float termb0 = p.termb[0];

  for (int step = 0; step < msteps; ++step) {
    // ---- P1: gi = x @ wihp^T ; gh = h @ whh^T (kept separate for n-gate) ----
    if (bid == 0 && tid == 0) *done = 1;
    for (int job = bid; job < 384; job += nb) {
      const int jj = (job < 192) ? job : job - 192;
      const int mt = jj / 48, nt = jj - mt * 48;
      float acc[4][4];
      float* C;
      if (job < 192) {
        gemm_tile<64, 64>(xbuf + mt * 64 * XDP_, XDP_,
                          wihp + nt * 64 * XDP_, XDP_, XDP_, sA, sB, acc);
        C = gi;
      } else {
        gemm_tile<64, 64>(hbuf + mt * 64 * HID_, HID_,
                          p.whh + nt * 64 * HID_, HID_, HID_, sA, sB, acc);
        C = gh;
      }
      const int tx = tid & 15, ty = tid >> 4;
      #pragma unroll
      for (int i = 0; i < 4; ++i)
        st4(C + (mt * 64 + ty * 4 + i) * H3_ + nt * 64 + tx * 4, acc[i]);
    }
    gg.sync();
    // ---- P2: gates, h update (in place), count += sigmoid(inc), term check ----
    for (int r = bid; r < B_; r += nb) {
      const int i = tid * 4;
      const float* gir = gi + r * H3_;
      const float* ghr = gh + r * H3_;
      float xr[4], hr[4], xz[4], hz[4], xn[4], hn[4];
      ld4(xr, gir + i);        ld4(hr, ghr + i);
      ld4(xz, gir + 1024 + i); ld4(hz, ghr + 1024 + i);
      ld4(xn, gir + 2048 + i); ld4(hn, ghr + 2048 + i);
      float bri[4], brh[4], bzi[4], bzh[4], bni[4], bnh[4];
      ld4(bri, p.bih + i);        ld4(brh, p.bhh + i);
      ld4(bzi, p.bih + 1024 + i); ld4(bzh, p.bhh + 1024 + i);
      ld4(bni, p.bih + 2048 + i); ld4(bnh, p.bhh + 2048 + i);
      float hv[4], iw[4], tw[4], hnew[4];
      ld4(hv, hbuf + r * HID_ + i);
      ld4(iw, p.incw + i);
      ld4(tw, p.termw + i);
      float incd = 0.f, termd = 0.f;
      #pragma unroll
      for (int j = 0; j < 4; ++j) {
        float rr = sigm(xr[j] + bri[j] + hr[j] + brh[j]);
        float zz = sigm(xz[j] + bzi[j] + hz[j] + bzh[j]);
        float nn = tanhf(xn[j] + bni[j] + rr * (hn[j] + bnh[j]));
        float h2 = (1.f - zz) * nn + zz * hv[j];
        hnew[j] = h2;
        incd = fmaf(h2, iw[j], incd);
        termd = fmaf(h2, tw[j], termd);
      }
      st4(hbuf + r * HID_ + i, hnew);
      #pragma unroll
      for (int off = 32; off > 0; off >>= 1) {
        incd += __shfl_down(incd, off);
        termd += __shfl_down(termd, off);
      }
      if ((tid & 63) == 0) { rsum[tid >> 6] = incd; rsum[4 + (tid >> 6)] = termd; }
      __syncthreads();
      if (tid == 0) {
        float it = rsum[0] + rsum[1] + rsum[2] + rsum[3];
        float tt = rsum[4] + rsum[5] + rsum[6] + rsum[7];
        float cnt = p.out[r] + sigm(it + incb0);
        p.out[r] = cnt;                       // count accumulates in d_out
        xbuf[r * XDP_ + (IN_ + HW_)] = cnt;   // count column of x
        if (tt + termb0 <= 0.f) atomicAnd(done, 0);  // sigmoid(t)>0.5 <=> t>0
      }
      __syncthreads();
    }
    gg.sync();
    const int isdone = *done;
    // ---- P3: mask += sigmoid(h @ ww^T + wb), fused epilogue, dual-store to x ----
    for (int job = bid; job < 128; job += nb) {
      const int mt = job >> 5, nt = job & 31;
      float acc[4][2];
      gemm_tile<64, 32>(hbuf + mt * 64 * HID_, HID_,
                        p.ww + nt * 32 * HID_, HID_, HID_, sA, sB, acc);
      const int tx = tid & 15, ty = tid >> 4;
      #pragma unroll
      for (int i = 0; i < 4; ++i)
        #pragma unroll
        for (int j = 0; j < 2; ++j) {
          const int m = mt * 64 + ty * 4 + i;
          const int n = nt * 32 + tx * 2 + j;
          const float val = sigm(acc[i][j] + p.wb[n]);
          const int oi = B_ + m * HW_ + n;
          const float mnew = p.out[oi] + val;
          p.out[oi] = mnew;
          xbuf[m * XDP_ + IN_ + n] = mnew;
        }
    }
    gg.sync();
    if (isdone) break;  // uniform across all blocks
  }
}

extern "C" void kernel_launch(void* const* d_in, const int* in_sizes, int n_in,
                              void* d_out, int out_size, void* d_ws, size_t ws_size,
                              hipStream_t stream) {
  (void)in_sizes; (void)n_in; (void)out_size; (void)ws_size;
  Params prm;
  prm.grid = (const float*)d_in[0];
  prm.c1w  = (const float*)d_in[1];
  prm.c1b  = (const float*)d_in[2];
  prm.c2w  = (const float*)d_in[3];
  prm.c2b  = (const float*)d_in[4];
  prm.linw = (const float*)d_in[5];
  prm.linb = (const float*)d_in[6];
  prm.wih  = (const float*)d_in[7];
  prm.whh  = (const float*)d_in[8];
  prm.bih  = (const float*)d_in[9];
  prm.bhh  = (const float*)d_in[10];
  prm.ww   = (const float*)d_in[11];
  prm.wb   = (const float*)d_in[12];
  prm.incw = (const float*)d_in[13];
  prm.incb = (const float*)d_in[14];
  prm.termw = (const float*)d_in[15];
  prm.termb = (const float*)d_in[16];
  prm.max_steps = (const int*)d_in[17];
  prm.out = (float*)d_out;
  prm.ws = (float*)d_ws;

  hipLaunchKernelGGL(conv_kernel, dim3(B_), dim3(NT_), 0, stream, prm);

  int occ = 1;
  (void)hipOccupancyMaxActiveBlocksPerMultiprocessor(&occ, (const void*)main_kernel, NT_, 0);
  if (occ < 1) occ = 1;
  int nb = occ * 256;           // 256 CUs on MI355X
  if (nb > 512) nb = 512;       // job count cap
  void* args[] = {(void*)&prm};
  (void)hipLaunchCooperativeKernel((const void*)main_kernel, dim3(nb), dim3(NT_),
                                   args, 0, stream);
}

// Round 2
// 426.559 us; speedup vs baseline: 1.9346x; 1.9346x over previous
//
#include <hip/hip_runtime.h>
#include <hip/hip_cooperative_groups.h>

namespace cg = cooperative_groups;

#define DEVI static __device__ __forceinline__

constexpr int NT_ = 256;
constexpr int B_ = 256, HW_ = 1024, IN_ = 512, HID_ = 1024, H3_ = 3072;
constexpr int XD_ = 1537;
constexpr int FLAT_ = 16384;

// ---- workspace layout (float offsets) ----
constexpr int OFF_PART = 0;                  // 16 * 256*512 split-K partials
constexpr int OFF_FEAT = 2097152;            // 256*512
constexpr int OFF_WIHF = 2228224;            // 3072*512   wih[:, :512] repacked
constexpr int OFF_WIHM = 3801088;            // 3072*1024  wih[:, 512:1536] repacked
constexpr int OFF_WIHC = 6946816;            // 3072       wih[:, 1536]
constexpr int OFF_CNTD = 6949888;            // 256
constexpr int OFF_DONE = 6950144;            // 2 ints (16 floats reserved)
constexpr int OFF_C2   = 6950160;            // 256*16384 conv2 out (dead after lin)
// state block aliases the dead c2f region:
constexpr int OFF_GI   = OFF_C2;             // 256*3072
constexpr int OFF_GH   = OFF_GI + 786432;    // 256*3072
constexpr int OFF_H0   = OFF_GI + 1572864;   // 256*1024
constexpr int OFF_H1   = OFF_GI + 1835008;   // 256*1024
constexpr int OFF_WSIG = OFF_GI + 2097152;   // 256*1024

struct Params {
  const float* grid;
  const float* c1w; const float* c1b;
  const float* c2w; const float* c2b;
  const float* linw; const float* linb;
  const float* wih; const float* whh;
  const float* bih; const float* bhh;
  const float* ww;  const float* wb;
  const float* incw; const float* incb;
  const float* termw; const float* termb;
  const int* max_steps;
  float* out;   // [0:256) count, [256:262400) mask [256][1024]
  float* ws;
};

DEVI float sigm(float x) { return 1.f / (1.f + __expf(-x)); }
DEVI float tanh_(float x) { return 1.f - 2.f / (__expf(2.f * x) + 1.f); }
DEVI float2 ld2(const float* p) { return *(const float2*)p; }
DEVI void ld4(float* d, const float* p) {
  float4 v = *(const float4*)p; d[0] = v.x; d[1] = v.y; d[2] = v.z; d[3] = v.w;
}

// ---------------- conv front-end: one block per batch element ----------------
__global__ __launch_bounds__(NT_) void conv_kernel(Params p) {
  __shared__ float s_in[34 * 34];
  __shared__ float s_c1[8 * 34 * 34];
  const int b = blockIdx.x;
  const int tid = threadIdx.x;
  for (int i = tid; i < 34 * 34; i += NT_) s_in[i] = 0.f;
  for (int i = tid; i < 8 * 34 * 34; i += NT_) s_c1[i] = 0.f;
  __syncthreads();
  for (int i = tid; i < 1024; i += NT_) {
    int y = i >> 5, x = i & 31;
    s_in[(y + 1) * 34 + (x + 1)] = p.grid[b * 1024 + i];
  }
  __syncthreads();
  const int pos0 = tid * 4;
  const int y = pos0 >> 5, x0 = pos0 & 31;
  {
    float win[3][6];
    #pragma unroll
    for (int dy = 0; dy < 3; ++dy)
      #pragma unroll
      for (int c = 0; c < 6; ++c) win[dy][c] = s_in[(y + dy) * 34 + x0 + c];
    float acc[8][4];
    #pragma unroll
    for (int oc = 0; oc < 8; ++oc)
      #pragma unroll
      for (int i = 0; i < 4; ++i) acc[oc][i] = p.c1b[oc];
    #pragma unroll
    for (int oc = 0; oc < 8; ++oc)
      #pragma unroll
      for (int dy = 0; dy < 3; ++dy)
        #pragma unroll
        for (int dx = 0; dx < 3; ++dx) {
          float w = p.c1w[oc * 9 + dy * 3 + dx];
          #pragma unroll
          for (int i = 0; i < 4; ++i)
            acc[oc][i] = fmaf(w, win[dy][i + dx], acc[oc][i]);
        }
    #pragma unroll
    for (int oc = 0; oc < 8; ++oc)
      #pragma unroll
      for (int i = 0; i < 4; ++i)
        s_c1[oc * 1156 + (y + 1) * 34 + (x0 + i + 1)] = fmaxf(acc[oc][i], 0.f);
  }
  __syncthreads();
  {
    float acc[16][4];
    #pragma unroll
    for (int oc = 0; oc < 16; ++oc)
      #pragma unroll
      for (int i = 0; i < 4; ++i) acc[oc][i] = p.c2b[oc];
    for (int ic = 0; ic < 8; ++ic) {
      float win[3][6];
      #pragma unroll
      for (int dy = 0; dy < 3; ++dy)
        #pragma unroll
        for (int c = 0; c < 6; ++c)
          win[dy][c] = s_c1[ic * 1156 + (y + dy) * 34 + x0 + c];
      #pragma unroll
      for (int oc = 0; oc < 16; ++oc)
        #pragma unroll
        for (int dy = 0; dy < 3; ++dy)
          #pragma unroll
          for (int dx = 0; dx < 3; ++dx) {
            float w = p.c2w[oc * 72 + ic * 9 + dy * 3 + dx];
            #pragma unroll
            for (int i = 0; i < 4; ++i)
              acc[oc][i] = fmaf(w, win[dy][i + dx], acc[oc][i]);
          }
    }
    float* dst = p.ws + OFF_C2 + b * FLAT_;
    #pragma unroll
    for (int oc = 0; oc < 16; ++oc) {
      float4 v = {fmaxf(acc[oc][0], 0.f), fmaxf(acc[oc][1], 0.f),
                  fmaxf(acc[oc][2], 0.f), fmaxf(acc[oc][3], 0.f)};
      *(float4*)(dst + oc * 1024 + pos0) = v;
    }
  }
}

// ---------------- prep: repack wih slices, preset done[0] ----------------
__global__ __launch_bounds__(NT_) void prep_kernel(Params p) {
  const int gt = blockIdx.x * NT_ + threadIdx.x;
  const int gs = gridDim.x * NT_;
  float* wihf = p.ws + OFF_WIHF;
  float* wihm = p.ws + OFF_WIHM;
  float* wihc = p.ws + OFF_WIHC;
  for (int i = gt; i < H3_ * IN_; i += gs) {
    int n = i >> 9, k = i & 511;
    wihf[i] = p.wih[n * XD_ + k];
  }
  for (int i = gt; i < H3_ * HID_; i += gs) {
    int n = i >> 10, k = i & 1023;
    wihm[i] = p.wih[n * XD_ + 512 + k];
  }
  for (int i = gt; i < H3_; i += gs) wihc[i] = p.wih[i * XD_ + 1536];
  if (gt == 0) ((int*)(p.ws + OFF_DONE))[0] = 1;
}

// ---- double-buffered 64x64 f32 GEMM tile: C[m][n] = sum_k A[m][k]*Bw[n][k] ----
// As/Bs each 2*16*68 floats. 256 threads, 4x4 micro-tile per thread.
DEVI void gemm_db(const float* __restrict__ A, int lda,
                  const float* __restrict__ Bw, int ldb, int K,
                  float* __restrict__ As, float* __restrict__ Bs,
                  float (&acc)[4][4]) {
  constexpr int P = 68;
  const int tid = threadIdx.x;
  const int tx = tid & 15, ty = tid >> 4;
  const int lr = tid >> 2, lk = (tid & 3) << 2;
  #pragma unroll
  for (int i = 0; i < 4; ++i)
    #pragma unroll
    for (int j = 0; j < 4; ++j) acc[i][j] = 0.f;
  float4 va = *(const float4*)(A + lr * lda + lk);
  float4 vb = *(const float4*)(Bw + lr * ldb + lk);
  As[(lk + 0) * P + lr] = va.x; As[(lk + 1) * P + lr] = va.y;
  As[(lk + 2) * P + lr] = va.z; As[(lk + 3) * P + lr] = va.w;
  Bs[(lk + 0) * P + lr] = vb.x; Bs[(lk + 1) * P + lr] = vb.y;
  Bs[(lk + 2) * P + lr] = vb.z; Bs[(lk + 3) * P + lr] = vb.w;
  __syncthreads();
  int cur = 0;
  for (int k0 = 16; k0 < K; k0 += 16) {
    va = *(const float4*)(A + lr * lda + k0 + lk);
    vb = *(const float4*)(Bw + lr * ldb + k0 + lk);
    const float* as = As + cur * (16 * P);
    const float* bs = Bs + cur * (16 * P);
    #pragma unroll
    for (int kk = 0; kk < 16; ++kk) {
      float a[4], b[4];
      ld4(a, as + kk * P + ty * 4);
      ld4(b, bs + kk * P + tx * 4);
      #pragma unroll
      for (int i = 0; i < 4; ++i)
        #pragma unroll
        for (int j = 0; j < 4; ++j) acc[i][j] = fmaf(a[i], b[j], acc[i][j]);
    }
    __syncthreads();
    float* asw = As + (cur ^ 1) * (16 * P);
    float* bsw = Bs + (cur ^ 1) * (16 * P);
    asw[(lk + 0) * P + lr] = va.x; asw[(lk + 1) * P + lr] = va.y;
    asw[(lk + 2) * P + lr] = va.z; asw[(lk + 3) * P + lr] = va.w;
    bsw[(lk + 0) * P + lr] = vb.x; bsw[(lk + 1) * P + lr] = vb.y;
    bsw[(lk + 2) * P + lr] = vb.z; bsw[(lk + 3) * P + lr] = vb.w;
    __syncthreads();
    cur ^= 1;
  }
  const float* as = As + cur * (16 * P);
  const float* bs = Bs + cur * (16 * P);
  #pragma unroll
  for (int kk = 0; kk < 16; ++kk) {
    float a[4], b[4];
    ld4(a, as + kk * P + ty * 4);
    ld4(b, bs + kk * P + tx * 4);
    #pragma unroll
    for (int i = 0; i < 4; ++i)
      #pragma unroll
      for (int j = 0; j < 4; ++j) acc[i][j] = fmaf(a[i], b[j], acc[i][j]);
  }
}

// ---------------- linear split-K: part[ks] = c2f_tile @ linw_tile^T ----------
__global__ __launch_bounds__(NT_) void lin_kernel(Params p) {
  __shared__ __align__(16) float smem[4352];
  float* As = smem;
  float* Bs = smem + 2176;
  const int bid = blockIdx.x;              // 512 jobs
  const int ks = bid & 15;
  const int t = bid >> 4;
  const int mt = t >> 3, nt = t & 7;
  const float* c2f = p.ws + OFF_C2;
  float acc[4][4];
  gemm_db(c2f + mt * 64 * FLAT_ + ks * 1024, FLAT_,
          p.linw + nt * 64 * FLAT_ + ks * 1024, FLAT_, 1024, As, Bs, acc);
  float* part = p.ws + OFF_PART + ks * (B_ * IN_);
  const int tx = threadIdx.x & 15, ty = threadIdx.x >> 4;
  #pragma unroll
  for (int i = 0; i < 4; ++i) {
    float4 v = {acc[i][0], acc[i][1], acc[i][2], acc[i][3]};
    *(float4*)(part + (mt * 64 + ty * 4 + i) * IN_ + nt * 64 + tx * 4) = v;
  }
}

// ---------------- reduce split-K -> feat ----------------
__global__ __launch_bounds__(NT_) void red_kernel(Params p) {
  const int i = blockIdx.x * NT_ + threadIdx.x;   // 512 blocks -> exact
  if (i >= B_ * IN_) return;
  const int o = i & (IN_ - 1);
  const float* part = p.ws + OFF_PART;
  float s = p.linb[o];
  #pragma unroll
  for (int ks = 0; ks < 16; ++ks) s += part[ks * (B_ * IN_) + i];
  (p.ws + OFF_FEAT)[i] = s;
}

// ---------------- gi_base = feat @ wihf^T (192 jobs) ----------------
__global__ __launch_bounds__(NT_) void a1_kernel(Params p) {
  __shared__ __align__(16) float smem[4352];
  float* As = smem;
  float* Bs = smem + 2176;
  const int bid = blockIdx.x;              // 192 jobs: 4 mt x 48 nt
  const int mt = bid / 48, nt = bid - mt * 48;
  float acc[4][4];
  gemm_db(p.ws + OFF_FEAT + mt * 64 * IN_, IN_,
          p.ws + OFF_WIHF + nt * 64 * IN_, IN_, IN_, As, Bs, acc);
  float* gi = p.ws + OFF_GI;
  const int tx = threadIdx.x & 15, ty = threadIdx.x >> 4;
  #pragma unroll
  for (int i = 0; i < 4; ++i) {
    float4 v = {acc[i][0], acc[i][1], acc[i][2], acc[i][3]};
    *(float4*)(gi + (mt * 64 + ty * 4 + i) * H3_ + nt * 64 + tx * 4) = v;
  }
}

// ---------------- B phase: fused gates + write-GEMM + dots ----------------
DEVI void b_job(const Params& p, float* sh2, float* swb,
                const float* gi, const float* gh, const float* hold,
                float* hnew, float* wsig, const float* cntd_unused, float* cntd,
                int* dflag, int job) {
  const int tid = threadIdx.x;
  const int mt = job >> 3, nt = job & 7;
  const int r0 = mt * 8, c0 = nt * 128;
  const int gr = tid >> 5;                 // 0..7
  const int gk = (tid & 31) * 2;           // 0..62
  const int wr = tid & 7;
  const int wc = (tid >> 3) * 4;           // 0..124
  const int row = r0 + gr;
  const float* giR = gi + row * H3_;
  const float* ghR = gh + row * H3_;
  const float* hR = hold + row * HID_;
  float* hW = hnew + row * HID_;
  float acc[4] = {0.f, 0.f, 0.f, 0.f};
  float incd = 0.f, termd = 0.f;
  const bool wh = (nt == 0);
  for (int kc = 0; kc < HID_; kc += 64) {
    // gates (global reads, no LDS dependence)
    float2 gxr = ld2(giR + kc + gk);
    float2 gxz = ld2(giR + 1024 + kc + gk);
    float2 gxn = ld2(giR + 2048 + kc + gk);
    float2 ghr = ld2(ghR + kc + gk);
    float2 ghz = ld2(ghR + 1024 + kc + gk);
    float2 ghn = ld2(ghR + 2048 + kc + gk);
    float2 hol = ld2(hR + kc + gk);
    float2 bri = ld2(p.bih + kc + gk);
    float2 brh = ld2(p.bhh + kc + gk);
    float2 bzi = ld2(p.bih + 1024 + kc + gk);
    float2 bzh = ld2(p.bhh + 1024 + kc + gk);
    float2 bni = ld2(p.bih + 2048 + kc + gk);
    float2 bnh = ld2(p.bhh + 2048 + kc + gk);
    float2 iw = ld2(p.incw + kc + gk);
    float2 tw = ld2(p.termw + kc + gk);
    float h2[2];
    {
      float rr = sigm(gxr.x + bri.x + ghr.x + brh.x);
      float zz = sigm(gxz.x + bzi.x + ghz.x + bzh.x);
      float nn = tanh_(gxn.x + bni.x + rr * (ghn.x + bnh.x));
      h2[0] = (1.f - zz) * nn + zz * hol.x;
      rr = sigm(gxr.y + bri.y + ghr.y + brh.y);
      zz = sigm(gxz.y + bzi.y + ghz.y + bzh.y);
      nn = tanh_(gxn.y + bni.y + rr * (ghn.y + bnh.y));
      h2[1] = (1.f - zz) * nn + zz * hol.y;
    }
    incd = fmaf(h2[0], iw.x, fmaf(h2[1], iw.y, incd));
    termd = fmaf(h2[0], tw.x, fmaf(h2[1], tw.y, termd));
    // ww chunk loads (128 cols x 64 k)
    float4 wreg[8];
    #pragma unroll
    for (int it = 0; it < 8; ++it) {
      int id = tid + it * 256;
      int c = id >> 4, k4 = (id & 15) * 4;
      wreg[it] = *(const float4*)(p.ww + (c0 + c) * HID_ + kc + k4);
    }
    __syncthreads();   // previous chunk's FMA readers done
    sh2[gr * 68 + gk] = h2[0];
    sh2[gr * 68 + gk + 1] = h2[1];
    #pragma unroll
    for (int it = 0; it < 8; ++it) {
      int id = tid + it * 256;
      int c = id >> 4, k4 = (id & 15) * 4;
      swb[(k4 + 0) * 132 + c] = wreg[it].x;
      swb[(k4 + 1) * 132 + c] = wreg[it].y;
      swb[(k4 + 2) * 132 + c] = wreg[it].z;
      swb[(k4 + 3) * 132 + c] = wreg[it].w;
    }
    if (wh) *(float2*)(hW + kc + gk) = make_float2(h2[0], h2[1]);
    __syncthreads();   // LDS visible
    #pragma unroll 8
    for (int kk = 0; kk < 64; ++kk) {
      float a = sh2[wr * 68 + kk];
      float4 b = *(const float4*)(swb + kk * 132 + wc);
      acc[0] = fmaf(a, b.x, acc[0]);
      acc[1] = fmaf(a, b.y, acc[1]);
      acc[2] = fmaf(a, b.z, acc[2]);
      acc[3] = fmaf(a, b.w, acc[3]);
    }
  }
  // per-row inc/term dots (nt==0 only), reduce across 32 lanes per row
  if (wh) {
    #pragma unroll
    for (int off = 16; off > 0; off >>= 1) {
      incd += __shfl_down(incd, off, 32);
      termd += __shfl_down(termd, off, 32);
    }
    if ((tid & 31) == 0) {
      float cd = sigm(incd + p.incb[0]);
      cntd[row] = cd;
      p.out[row] += cd;
      if (termd + p.termb[0] <= 0.f) atomicAnd(dflag, 0);
    }
  }
  // mask epilogue + wsig
  {
    const int m = r0 + wr;
    float4 wb4 = *(const float4*)(p.wb + c0 + wc);
    float4 sv = {sigm(acc[0] + wb4.x), sigm(acc[1] + wb4.y),
                 sigm(acc[2] + wb4.z), sigm(acc[3] + wb4.w)};
    float* op = p.out + B_ + m * HW_ + c0 + wc;
    float4 ov = *(float4*)op;
    ov.x += sv.x; ov.y += sv.y; ov.z += sv.z; ov.w += sv.w;
    *(float4*)op = ov;
    *(float4*)(wsig + m * HID_ + c0 + wc) = sv;
  }
}

// ---------------- cooperative step loop ----------------
__global__ __launch_bounds__(NT_, 2) void step_kernel(Params p) {
  cg::grid_group gg = cg::this_grid();
  __shared__ __align__(16) float smem[8992];
  float* As = smem;             // 2*16*68
  float* Bs = smem + 2176;      // 2*16*68
  float* sh2 = smem;            // 8*68 = 544
  float* swb = smem + 544;      // 64*132 = 8448
  float* const ws = p.ws;
  float* const gi = ws + OFF_GI;
  float* const gh = ws + OFF_GH;
  float* const h0 = ws + OFF_H0;
  float* const h1 = ws + OFF_H1;
  float* const wsig = ws + OFF_WSIG;
  float* const cntd = ws + OFF_CNTD;
  const float* const wihm = ws + OFF_WIHM;
  const float* const wihc = ws + OFF_WIHC;
  int* const done = (int*)(ws + OFF_DONE);
  const int tid = threadIdx.x;
  const int bid = blockIdx.x;
  const int nb = gridDim.x;
  const int tx = tid & 15, ty = tid >> 4;
  const int msteps = p.max_steps[0];

  for (int step = 0; step < msteps; ++step) {
    float* hcur = (step & 1) ? h1 : h0;
    float* hnxt = (step & 1) ? h0 : h1;
    if (step > 0) {
      // A phase: gi += wsig@wihm^T + cntd*wihc ; gh = h@whh^T
      for (int job = bid; job < 384; job += nb) {
        float acc[4][4];
        if (job < 192) {
          const int mt = job / 48, nt = job - mt * 48;
          gemm_db(wsig + mt * 64 * HID_, HID_,
                  wihm + nt * 64 * HID_, HID_, HID_, As, Bs, acc);
          #pragma unroll
          for (int i = 0; i < 4; ++i) {
            const int m = mt * 64 + ty * 4 + i;
            const float cd = cntd[m];
            float4 wc4 = *(const float4*)(wihc + nt * 64 + tx * 4);
            float* gp = gi + m * H3_ + nt * 64 + tx * 4;
            float4 g = *(float4*)gp;
            g.x += acc[i][0] + cd * wc4.x;
            g.y += acc[i][1] + cd * wc4.y;
            g.z += acc[i][2] + cd * wc4.z;
            g.w += acc[i][3] + cd * wc4.w;
            *(float4*)gp = g;
          }
        } else {
          const int j = job - 192;
          const int mt = j / 48, nt = j - mt * 48;
          gemm_db(hcur + mt * 64 * HID_, HID_,
                  p.whh + nt * 64 * HID_, HID_, HID_, As, Bs, acc);
          #pragma unroll
          for (int i = 0; i < 4; ++i) {
            float4 v = {acc[i][0], acc[i][1], acc[i][2], acc[i][3]};
            *(float4*)(gh + (mt * 64 + ty * 4 + i) * H3_ + nt * 64 + tx * 4) = v;
          }
        }
        __syncthreads();   // LDS reuse safety across grid-stride jobs
      }
      gg.sync();
    }
    // B phase
    for (int job = bid; job < 256; job += nb)
      b_job(p, sh2, swb, gi, gh, hcur, hnxt, wsig, nullptr, cntd,
            &done[step & 1], job);
    if (bid == 0 && tid == 0) done[(step + 1) & 1] = 1;
    gg.sync();
    if (*(volatile int*)&done[step & 1]) break;
  }
}

extern "C" void kernel_launch(void* const* d_in, const int* in_sizes, int n_in,
                              void* d_out, int out_size, void* d_ws, size_t ws_size,
                              hipStream_t stream) {
  (void)in_sizes; (void)n_in; (void)ws_size;
  Params prm;
  prm.grid = (const float*)d_in[0];
  prm.c1w  = (const float*)d_in[1];
  prm.c1b  = (const float*)d_in[2];
  prm.c2w  = (const float*)d_in[3];
  prm.c2b  = (const float*)d_in[4];
  prm.linw = (const float*)d_in[5];
  prm.linb = (const float*)d_in[6];
  prm.wih  = (const float*)d_in[7];
  prm.whh  = (const float*)d_in[8];
  prm.bih  = (const float*)d_in[9];
  prm.bhh  = (const float*)d_in[10];
  prm.ww   = (const float*)d_in[11];
  prm.wb   = (const float*)d_in[12];
  prm.incw = (const float*)d_in[13];
  prm.incb = (const float*)d_in[14];
  prm.termw = (const float*)d_in[15];
  prm.termb = (const float*)d_in[16];
  prm.max_steps = (const int*)d_in[17];
  prm.out = (float*)d_out;
  prm.ws = (float*)d_ws;
  float* ws = (float*)d_ws;

  hipLaunchKernelGGL(conv_kernel, dim3(B_), dim3(NT_), 0, stream, prm);
  hipLaunchKernelGGL(prep_kernel, dim3(512), dim3(NT_), 0, stream, prm);
  hipLaunchKernelGGL(lin_kernel, dim3(512), dim3(NT_), 0, stream, prm);
  hipLaunchKernelGGL(red_kernel, dim3(512), dim3(NT_), 0, stream, prm);
  // zero: gh (B step0 reads zeros), h0, out accumulators (all after lin reads c2f)
  hipMemsetAsync(ws + OFF_GH, 0, 786432 * sizeof(float), stream);
  hipMemsetAsync(ws + OFF_H0, 0, 262144 * sizeof(float), stream);
  hipMemsetAsync(d_out, 0, (size_t)out_size * sizeof(float), stream);
  hipLaunchKernelGGL(a1_kernel, dim3(192), dim3(NT_), 0, stream, prm);

  int occ = 1;
  (void)hipOccupancyMaxActiveBlocksPerMultiprocessor(&occ, (const void*)step_kernel, NT_, 0);
  int nb = (occ >= 2) ? 384 : 256;
  void* args[] = {(void*)&prm};
  (void)hipLaunchCooperativeKernel((const void*)step_kernel, dim3(nb), dim3(NT_),
                                   args, 0, stream);
}

// Round 3
// 337.617 us; speedup vs baseline: 2.4443x; 1.2634x over previous
//
#include <hip/hip_runtime.h>
#include <hip/hip_cooperative_groups.h>

namespace cg = cooperative_groups;

#define DEVI static __device__ __forceinline__

constexpr int NT_ = 256;
constexpr int B_ = 256, HW_ = 1024, IN_ = 512, HID_ = 1024, H3_ = 3072;
constexpr int XD_ = 1537;
constexpr int FLAT_ = 16384;

// ---- workspace layout (float offsets) ----
constexpr int OFF_PART = 0;                  // 16 * 256*512 split-K partials
constexpr int OFF_FEAT = 2097152;            // 256*512
constexpr int OFF_WIHF = 2228224;            // 3072*512
constexpr int OFF_WIHM = 3801088;            // 3072*1024
constexpr int OFF_WIHC = 6946816;            // 3072
constexpr int OFF_CNTD = 6949888;            // 256
constexpr int OFF_FLAGS = 6950144;           // 128 ints: flags[t]=1 => terminated at/before t
constexpr int OFF_C2   = 6950272;            // 256*16384 conv2 out (dead after lin)
// state aliases dead c2f region:
constexpr int OFF_GI   = OFF_C2;             // 256*3072
constexpr int OFF_GH   = OFF_GI + 786432;    // 256*3072
constexpr int OFF_H0   = OFF_GI + 1572864;   // 256*1024
constexpr int OFF_H1   = OFF_GI + 1835008;   // 256*1024
constexpr int OFF_WSIG = OFF_GI + 2097152;   // 256*1024

struct Params {
  const float* grid;
  const float* c1w; const float* c1b;
  const float* c2w; const float* c2b;
  const float* linw; const float* linb;
  const float* wih; const float* whh;
  const float* bih; const float* bhh;
  const float* ww;  const float* wb;
  const float* incw; const float* incb;
  const float* termw; const float* termb;
  const int* max_steps;
  float* out;   // [0:256) count, [256:262400) mask [256][1024]
  float* ws;
};

DEVI float sigm(float x) { return 1.f / (1.f + __expf(-x)); }
DEVI float tanh_(float x) { return 1.f - 2.f / (__expf(2.f * x) + 1.f); }
DEVI float2 ld2(const float* p) { return *(const float2*)p; }
DEVI void ld4(float* d, const float* p) {
  float4 v = *(const float4*)p; d[0] = v.x; d[1] = v.y; d[2] = v.z; d[3] = v.w;
}

// ---------------- conv front-end ----------------
__global__ __launch_bounds__(NT_) void conv_kernel(Params p) {
  __shared__ float s_in[34 * 34];
  __shared__ float s_c1[8 * 34 * 34];
  const int b = blockIdx.x;
  const int tid = threadIdx.x;
  for (int i = tid; i < 34 * 34; i += NT_) s_in[i] = 0.f;
  for (int i = tid; i < 8 * 34 * 34; i += NT_) s_c1[i] = 0.f;
  __syncthreads();
  for (int i = tid; i < 1024; i += NT_) {
    int y = i >> 5, x = i & 31;
    s_in[(y + 1) * 34 + (x + 1)] = p.grid[b * 1024 + i];
  }
  __syncthreads();
  const int pos0 = tid * 4;
  const int y = pos0 >> 5, x0 = pos0 & 31;
  {
    float win[3][6];
    #pragma unroll
    for (int dy = 0; dy < 3; ++dy)
      #pragma unroll
      for (int c = 0; c < 6; ++c) win[dy][c] = s_in[(y + dy) * 34 + x0 + c];
    float acc[8][4];
    #pragma unroll
    for (int oc = 0; oc < 8; ++oc)
      #pragma unroll
      for (int i = 0; i < 4; ++i) acc[oc][i] = p.c1b[oc];
    #pragma unroll
    for (int oc = 0; oc < 8; ++oc)
      #pragma unroll
      for (int dy = 0; dy < 3; ++dy)
        #pragma unroll
        for (int dx = 0; dx < 3; ++dx) {
          float w = p.c1w[oc * 9 + dy * 3 + dx];
          #pragma unroll
          for (int i = 0; i < 4; ++i)
            acc[oc][i] = fmaf(w, win[dy][i + dx], acc[oc][i]);
        }
    #pragma unroll
    for (int oc = 0; oc < 8; ++oc)
      #pragma unroll
      for (int i = 0; i < 4; ++i)
        s_c1[oc * 1156 + (y + 1) * 34 + (x0 + i + 1)] = fmaxf(acc[oc][i], 0.f);
  }
  __syncthreads();
  {
    float acc[16][4];
    #pragma unroll
    for (int oc = 0; oc < 16; ++oc)
      #pragma unroll
      for (int i = 0; i < 4; ++i) acc[oc][i] = p.c2b[oc];
    for (int ic = 0; ic < 8; ++ic) {
      float win[3][6];
      #pragma unroll
      for (int dy = 0; dy < 3; ++dy)
        #pragma unroll
        for (int c = 0; c < 6; ++c)
          win[dy][c] = s_c1[ic * 1156 + (y + dy) * 34 + x0 + c];
      #pragma unroll
      for (int oc = 0; oc < 16; ++oc)
        #pragma unroll
        for (int dy = 0; dy < 3; ++dy)
          #pragma unroll
          for (int dx = 0; dx < 3; ++dx) {
            float w = p.c2w[oc * 72 + ic * 9 + dy * 3 + dx];
            #pragma unroll
            for (int i = 0; i < 4; ++i)
              acc[oc][i] = fmaf(w, win[dy][i + dx], acc[oc][i]);
          }
    }
    float* dst = p.ws + OFF_C2 + b * FLAT_;
    #pragma unroll
    for (int oc = 0; oc < 16; ++oc) {
      float4 v = {fmaxf(acc[oc][0], 0.f), fmaxf(acc[oc][1], 0.f),
                  fmaxf(acc[oc][2], 0.f), fmaxf(acc[oc][3], 0.f)};
      *(float4*)(dst + oc * 1024 + pos0) = v;
    }
  }
}

// ---------------- prep: repack wih slices, init flags ----------------
__global__ __launch_bounds__(NT_) void prep_kernel(Params p) {
  const int gt = blockIdx.x * NT_ + threadIdx.x;
  const int gs = gridDim.x * NT_;
  float* wihf = p.ws + OFF_WIHF;
  float* wihm = p.ws + OFF_WIHM;
  float* wihc = p.ws + OFF_WIHC;
  int* flags = (int*)(p.ws + OFF_FLAGS);
  for (int i = gt; i < H3_ * IN_; i += gs) {
    int n = i >> 9, k = i & 511;
    wihf[i] = p.wih[n * XD_ + k];
  }
  for (int i = gt; i < H3_ * HID_; i += gs) {
    int n = i >> 10, k = i & 1023;
    wihm[i] = p.wih[n * XD_ + 512 + k];
  }
  for (int i = gt; i < H3_; i += gs) wihc[i] = p.wih[i * XD_ + 1536];
  for (int i = gt; i < 128; i += gs) flags[i] = 1;
}

// ---- double-buffered 64xBN f32 GEMM tile: C[m][n] = sum_k A[m][k]*Bw[n][k] ----
template <int BN>
DEVI void gemm_dbT(const float* __restrict__ A, int lda,
                   const float* __restrict__ Bw, int ldb, int K,
                   float* __restrict__ As, float* __restrict__ Bs,
                   float (&acc)[4][BN / 16]) {
  constexpr int PA = 68;
  constexpr int PB = (BN == 64) ? 68 : 36;
  constexpr int TN = BN / 16;
  const int tid = threadIdx.x;
  const int tx = tid & 15, ty = tid >> 4;
  const int lr = tid >> 2, lk = (tid & 3) << 2;
  const bool bload = (BN == 64) || (tid < 128);
  #pragma unroll
  for (int i = 0; i < 4; ++i)
    #pragma unroll
    for (int j = 0; j < TN; ++j) acc[i][j] = 0.f;
  float4 va = *(const float4*)(A + lr * lda + lk);
  float4 vb = {0, 0, 0, 0};
  if (bload) vb = *(const float4*)(Bw + lr * ldb + lk);
  As[(lk + 0) * PA + lr] = va.x; As[(lk + 1) * PA + lr] = va.y;
  As[(lk + 2) * PA + lr] = va.z; As[(lk + 3) * PA + lr] = va.w;
  if (bload) {
    Bs[(lk + 0) * PB + lr] = vb.x; Bs[(lk + 1) * PB + lr] = vb.y;
    Bs[(lk + 2) * PB + lr] = vb.z; Bs[(lk + 3) * PB + lr] = vb.w;
  }
  __syncthreads();
  int cur = 0;
  for (int k0 = 16; k0 < K; k0 += 16) {
    va = *(const float4*)(A + lr * lda + k0 + lk);
    if (bload) vb = *(const float4*)(Bw + lr * ldb + k0 + lk);
    const float* as = As + cur * (16 * PA);
    const float* bs = Bs + cur * (16 * PB);
    #pragma unroll
    for (int kk = 0; kk < 16; ++kk) {
      float a[4];
      ld4(a, as + kk * PA + ty * 4);
      if constexpr (TN == 4) {
        float b[4];
        ld4(b, bs + kk * PB + tx * 4);
        #pragma unroll
        for (int i = 0; i < 4; ++i)
          #pragma unroll
          for (int j = 0; j < 4; ++j) acc[i][j] = fmaf(a[i], b[j], acc[i][j]);
      } else {
        float2 b = ld2(bs + kk * PB + tx * 2);
        #pragma unroll
        for (int i = 0; i < 4; ++i) {
          acc[i][0] = fmaf(a[i], b.x, acc[i][0]);
          acc[i][1] = fmaf(a[i], b.y, acc[i][1]);
        }
      }
    }
    __syncthreads();
    float* asw = As + (cur ^ 1) * (16 * PA);
    asw[(lk + 0) * PA + lr] = va.x; asw[(lk + 1) * PA + lr] = va.y;
    asw[(lk + 2) * PA + lr] = va.z; asw[(lk + 3) * PA + lr] = va.w;
    if (bload) {
      float* bsw = Bs + (cur ^ 1) * (16 * PB);
      bsw[(lk + 0) * PB + lr] = vb.x; bsw[(lk + 1) * PB + lr] = vb.y;
      bsw[(lk + 2) * PB + lr] = vb.z; bsw[(lk + 3) * PB + lr] = vb.w;
    }
    __syncthreads();
    cur ^= 1;
  }
  const float* as = As + cur * (16 * PA);
  const float* bs = Bs + cur * (16 * PB);
  #pragma unroll
  for (int kk = 0; kk < 16; ++kk) {
    float a[4];
    ld4(a, as + kk * PA + ty * 4);
    if constexpr (TN == 4) {
      float b[4];
      ld4(b, bs + kk * PB + tx * 4);
      #pragma unroll
      for (int i = 0; i < 4; ++i)
        #pragma unroll
        for (int j = 0; j < 4; ++j) acc[i][j] = fmaf(a[i], b[j], acc[i][j]);
    } else {
      float2 b = ld2(bs + kk * PB + tx * 2);
      #pragma unroll
      for (int i = 0; i < 4; ++i) {
        acc[i][0] = fmaf(a[i], b.x, acc[i][0]);
        acc[i][1] = fmaf(a[i], b.y, acc[i][1]);
      }
    }
  }
}

// ---------------- linear split-K ----------------
__global__ __launch_bounds__(NT_) void lin_kernel(Params p) {
  __shared__ __align__(16) float smem[4352];
  float* As = smem;
  float* Bs = smem + 2176;
  const int bid = blockIdx.x;              // 512 jobs
  const int ks = bid & 15;
  const int t = bid >> 4;
  const int mt = t >> 3, nt = t & 7;
  const float* c2f = p.ws + OFF_C2;
  float acc[4][4];
  gemm_dbT<64>(c2f + mt * 64 * FLAT_ + ks * 1024, FLAT_,
               p.linw + nt * 64 * FLAT_ + ks * 1024, FLAT_, 1024, As, Bs, acc);
  float* part = p.ws + OFF_PART + ks * (B_ * IN_);
  const int tx = threadIdx.x & 15, ty = threadIdx.x >> 4;
  #pragma unroll
  for (int i = 0; i < 4; ++i) {
    float4 v = {acc[i][0], acc[i][1], acc[i][2], acc[i][3]};
    *(float4*)(part + (mt * 64 + ty * 4 + i) * IN_ + nt * 64 + tx * 4) = v;
  }
}

// ---------------- reduce split-K -> feat ----------------
__global__ __launch_bounds__(NT_) void red_kernel(Params p) {
  const int i = blockIdx.x * NT_ + threadIdx.x;   // 512 blocks exact
  const int o = i & (IN_ - 1);
  const float* part = p.ws + OFF_PART;
  float s = p.linb[o];
  #pragma unroll
  for (int ks = 0; ks < 16; ++ks) s += part[ks * (B_ * IN_) + i];
  (p.ws + OFF_FEAT)[i] = s;
}

// ---------------- gi_base = feat @ wihf^T (192 jobs) ----------------
__global__ __launch_bounds__(NT_) void a1_kernel(Params p) {
  __shared__ __align__(16) float smem[4352];
  float* As = smem;
  float* Bs = smem + 2176;
  const int bid = blockIdx.x;              // 192 jobs: 4 mt x 48 nt
  const int mt = bid / 48, nt = bid - mt * 48;
  float acc[4][4];
  gemm_dbT<64>(p.ws + OFF_FEAT + mt * 64 * IN_, IN_,
               p.ws + OFF_WIHF + nt * 64 * IN_, IN_, IN_, As, Bs, acc);
  float* gi = p.ws + OFF_GI;
  const int tx = threadIdx.x & 15, ty = threadIdx.x >> 4;
  #pragma unroll
  for (int i = 0; i < 4; ++i) {
    float4 v = {acc[i][0], acc[i][1], acc[i][2], acc[i][3]};
    *(float4*)(gi + (mt * 64 + ty * 4 + i) * H3_ + nt * 64 + tx * 4) = v;
  }
}

// ---------------- A phase as regular kernel: 768 jobs of 64x32 ----------------
__global__ __launch_bounds__(NT_) void stepA_kernel(Params p, int step) {
  if (((volatile int*)(p.ws + OFF_FLAGS))[step - 1]) return;
  __shared__ __align__(16) float smem[3328];   // As 2*16*68, Bs 2*16*36
  float* As = smem;
  float* Bs = smem + 2176;
  float* const gi = p.ws + OFF_GI;
  float* const gh = p.ws + OFF_GH;
  float* const wsig = p.ws + OFF_WSIG;
  float* const cntd = p.ws + OFF_CNTD;
  const float* const wihm = p.ws + OFF_WIHM;
  const float* const wihc = p.ws + OFF_WIHC;
  const float* hcur = p.ws + ((step & 1) ? OFF_H1 : OFF_H0);
  const int job = blockIdx.x;
  const int tx = threadIdx.x & 15, ty = threadIdx.x >> 4;
  float acc[4][2];
  if (job < 384) {
    const int mt = job / 96, nt = job - mt * 96;
    gemm_dbT<32>(wsig + mt * 64 * HID_, HID_,
                 wihm + nt * 32 * HID_, HID_, HID_, As, Bs, acc);
    #pragma unroll
    for (int i = 0; i < 4; ++i) {
      const int m = mt * 64 + ty * 4 + i;
      const int n = nt * 32 + tx * 2;
      const float cd = cntd[m];
      float2 wc2 = ld2(wihc + n);
      float* gp = gi + m * H3_ + n;
      float2 g = *(float2*)gp;
      g.x += acc[i][0] + cd * wc2.x;
      g.y += acc[i][1] + cd * wc2.y;
      *(float2*)gp = g;
    }
  } else {
    const int j = job - 384;
    const int mt = j / 96, nt = j - mt * 96;
    gemm_dbT<32>(hcur + mt * 64 * HID_, HID_,
                 p.whh + nt * 32 * HID_, HID_, HID_, As, Bs, acc);
    #pragma unroll
    for (int i = 0; i < 4; ++i)
      *(float2*)(gh + (mt * 64 + ty * 4 + i) * H3_ + nt * 32 + tx * 2) =
          make_float2(acc[i][0], acc[i][1]);
  }
}

// ---------------- B phase: fused gates + write-GEMM + dots ----------------
DEVI void b_job(const Params& p, float* sh2, float* swb,
                const float* gi, const float* gh, const float* hold,
                float* hnew, float* wsig, float* cntd, int* dflag, int job) {
  const int tid = threadIdx.x;
  const int mt = job >> 3, nt = job & 7;
  const int r0 = mt * 8, c0 = nt * 128;
  const int gr = tid >> 5;                 // 0..7
  const int gk = (tid & 31) * 2;           // 0..62
  const int wr = tid & 7;
  const int wc = (tid >> 3) * 4;           // 0..124
  const int row = r0 + gr;
  const float* giR = gi + row * H3_;
  const float* ghR = gh + row * H3_;
  const float* hR = hold + row * HID_;
  float* hW = hnew + row * HID_;
  float acc[4] = {0.f, 0.f, 0.f, 0.f};
  float incd = 0.f, termd = 0.f;
  const bool wh = (nt == 0);
  for (int kc = 0; kc < HID_; kc += 64) {
    float2 gxr = ld2(giR + kc + gk);
    float2 gxz = ld2(giR + 1024 + kc + gk);
    float2 gxn = ld2(giR + 2048 + kc + gk);
    float2 ghr = ld2(ghR + kc + gk);
    float2 ghz = ld2(ghR + 1024 + kc + gk);
    float2 ghn = ld2(ghR + 2048 + kc + gk);
    float2 hol = ld2(hR + kc + gk);
    float2 bri = ld2(p.bih + kc + gk);
    float2 brh = ld2(p.bhh + kc + gk);
    float2 bzi = ld2(p.bih + 1024 + kc + gk);
    float2 bzh = ld2(p.bhh + 1024 + kc + gk);
    float2 bni = ld2(p.bih + 2048 + kc + gk);
    float2 bnh = ld2(p.bhh + 2048 + kc + gk);
    float2 iw = ld2(p.incw + kc + gk);
    float2 tw = ld2(p.termw + kc + gk);
    float h2[2];
    {
      float rr = sigm(gxr.x + bri.x + ghr.x + brh.x);
      float zz = sigm(gxz.x + bzi.x + ghz.x + bzh.x);
      float nn = tanh_(gxn.x + bni.x + rr * (ghn.x + bnh.x));
      h2[0] = (1.f - zz) * nn + zz * hol.x;
      rr = sigm(gxr.y + bri.y + ghr.y + brh.y);
      zz = sigm(gxz.y + bzi.y + ghz.y + bzh.y);
      nn = tanh_(gxn.y + bni.y + rr * (ghn.y + bnh.y));
      h2[1] = (1.f - zz) * nn + zz * hol.y;
    }
    incd = fmaf(h2[0], iw.x, fmaf(h2[1], iw.y, incd));
    termd = fmaf(h2[0], tw.x, fmaf(h2[1], tw.y, termd));
    float4 wreg[8];
    #pragma unroll
    for (int it = 0; it < 8; ++it) {
      int id = tid + it * 256;
      int c = id >> 4, k4 = (id & 15) * 4;
      wreg[it] = *(const float4*)(p.ww + (c0 + c) * HID_ + kc + k4);
    }
    __syncthreads();
    sh2[gr * 68 + gk] = h2[0];
    sh2[gr * 68 + gk + 1] = h2[1];
    #pragma unroll
    for (int it = 0; it < 8; ++it) {
      int id = tid + it * 256;
      int c = id >> 4, k4 = (id & 15) * 4;
      swb[(k4 + 0) * 132 + c] = wreg[it].x;
      swb[(k4 + 1) * 132 + c] = wreg[it].y;
      swb[(k4 + 2) * 132 + c] = wreg[it].z;
      swb[(k4 + 3) * 132 + c] = wreg[it].w;
    }
    if (wh) *(float2*)(hW + kc + gk) = make_float2(h2[0], h2[1]);
    __syncthreads();
    #pragma unroll 8
    for (int kk = 0; kk < 64; ++kk) {
      float a = sh2[wr * 68 + kk];
      float4 b = *(const float4*)(swb + kk * 132 + wc);
      acc[0] = fmaf(a, b.x, acc[0]);
      acc[1] = fmaf(a, b.y, acc[1]);
      acc[2] = fmaf(a, b.z, acc[2]);
      acc[3] = fmaf(a, b.w, acc[3]);
    }
  }
  if (wh) {
    #pragma unroll
    for (int off = 16; off > 0; off >>= 1) {
      incd += __shfl_down(incd, off, 32);
      termd += __shfl_down(termd, off, 32);
    }
    if ((tid & 31) == 0) {
      float cd = sigm(incd + p.incb[0]);
      cntd[row] = cd;
      p.out[row] += cd;
      if (termd + p.termb[0] <= 0.f) atomicAnd(dflag, 0);
    }
  }
  {
    const int m = r0 + wr;
    float4 wb4 = *(const float4*)(p.wb + c0 + wc);
    float4 sv = {sigm(acc[0] + wb4.x), sigm(acc[1] + wb4.y),
                 sigm(acc[2] + wb4.z), sigm(acc[3] + wb4.w)};
    float* op = p.out + B_ + m * HW_ + c0 + wc;
    float4 ov = *(float4*)op;
    ov.x += sv.x; ov.y += sv.y; ov.z += sv.z; ov.w += sv.w;
    *(float4*)op = ov;
    *(float4*)(wsig + m * HID_ + c0 + wc) = sv;
  }
}

// ---------------- B phase as regular kernel: 256 jobs ----------------
__global__ __launch_bounds__(NT_, 2) void stepB_kernel(Params p, int step) {
  int* flags = (int*)(p.ws + OFF_FLAGS);
  if (step > 0 && ((volatile int*)flags)[step - 1]) return;
  __shared__ __align__(16) float smem[8992];
  float* sh2 = smem;
  float* swb = smem + 544;
  float* hcur = p.ws + ((step & 1) ? OFF_H1 : OFF_H0);
  float* hnxt = p.ws + ((step & 1) ? OFF_H0 : OFF_H1);
  b_job(p, sh2, swb, p.ws + OFF_GI, p.ws + OFF_GH, hcur, hnxt,
        p.ws + OFF_WSIG, p.ws + OFF_CNTD, &flags[step], blockIdx.x);
}

// ---------------- cooperative tail (steps >= start; usually exits) ----------
__global__ __launch_bounds__(NT_, 2) void tail_kernel(Params p, int start) {
  int* flags = (int*)(p.ws + OFF_FLAGS);
  if (((volatile int*)flags)[start - 1]) return;
  cg::grid_group gg = cg::this_grid();
  __shared__ __align__(16) float smem[8992];
  float* As = smem;             // 2*16*68
  float* Bs = smem + 2176;      // 2*16*68
  float* sh2 = smem;
  float* swb = smem + 544;
  float* const ws = p.ws;
  float* const gi = ws + OFF_GI;
  float* const gh = ws + OFF_GH;
  float* const wsig = ws + OFF_WSIG;
  float* const cntd = ws + OFF_CNTD;
  const float* const wihm = ws + OFF_WIHM;
  const float* const wihc = ws + OFF_WIHC;
  const int tid = threadIdx.x;
  const int bid = blockIdx.x;
  const int nb = gridDim.x;
  const int tx = tid & 15, ty = tid >> 4;
  const int msteps = p.max_steps[0];

  for (int step = start; step < msteps; ++step) {
    float* hcur = ws + ((step & 1) ? OFF_H1 : OFF_H0);
    float* hnxt = ws + ((step & 1) ? OFF_H0 : OFF_H1);
    for (int job = bid; job < 384; job += nb) {
      float acc[4][4];
      if (job < 192) {
        const int mt = job / 48, nt = job - mt * 48;
        gemm_dbT<64>(wsig + mt * 64 * HID_, HID_,
                     wihm + nt * 64 * HID_, HID_, HID_, As, Bs, acc);
        #pragma unroll
        for (int i = 0; i < 4; ++i) {
          const int m = mt * 64 + ty * 4 + i;
          const float cd = cntd[m];
          float4 wc4 = *(const float4*)(wihc + nt * 64 + tx * 4);
          float* gp = gi + m * H3_ + nt * 64 + tx * 4;
          float4 g = *(float4*)gp;
          g.x += acc[i][0] + cd * wc4.x;
          g.y += acc[i][1] + cd * wc4.y;
          g.z += acc[i][2] + cd * wc4.z;
          g.w += acc[i][3] + cd * wc4.w;
          *(float4*)gp = g;
        }
      } else {
        const int j = job - 192;
        const int mt = j / 48, nt = j - mt * 48;
        gemm_dbT<64>(hcur + mt * 64 * HID_, HID_,
                     p.whh + nt * 64 * HID_, HID_, HID_, As, Bs, acc);
        #pragma unroll
        for (int i = 0; i < 4; ++i) {
          float4 v = {acc[i][0], acc[i][1], acc[i][2], acc[i][3]};
          *(float4*)(gh + (mt * 64 + ty * 4 + i) * H3_ + nt * 64 + tx * 4) = v;
        }
      }
      __syncthreads();
    }
    gg.sync();
    for (int job = bid; job < 256; job += nb)
      b_job(p, sh2, swb, gi, gh, hcur, hnxt, wsig, cntd, &flags[step], job);
    gg.sync();
    if (((volatile int*)flags)[step]) break;
  }
}

extern "C" void kernel_launch(void* const* d_in, const int* in_sizes, int n_in,
                              void* d_out, int out_size, void* d_ws, size_t ws_size,
                              hipStream_t stream) {
  (void)in_sizes; (void)n_in; (void)ws_size;
  Params prm;
  prm.grid = (const float*)d_in[0];
  prm.c1w  = (const float*)d_in[1];
  prm.c1b  = (const float*)d_in[2];
  prm.c2w  = (const float*)d_in[3];
  prm.c2b  = (const float*)d_in[4];
  prm.linw = (const float*)d_in[5];
  prm.linb = (const float*)d_in[6];
  prm.wih  = (const float*)d_in[7];
  prm.whh  = (const float*)d_in[8];
  prm.bih  = (const float*)d_in[9];
  prm.bhh  = (const float*)d_in[10];
  prm.ww   = (const float*)d_in[11];
  prm.wb   = (const float*)d_in[12];
  prm.incw = (const float*)d_in[13];
  prm.incb = (const float*)d_in[14];
  prm.termw = (const float*)d_in[15];
  prm.termb = (const float*)d_in[16];
  prm.max_steps = (const int*)d_in[17];
  prm.out = (float*)d_out;
  prm.ws = (float*)d_ws;
  float* ws = (float*)d_ws;

  hipLaunchKernelGGL(conv_kernel, dim3(B_), dim3(NT_), 0, stream, prm);
  hipLaunchKernelGGL(prep_kernel, dim3(512), dim3(NT_), 0, stream, prm);
  hipLaunchKernelGGL(lin_kernel, dim3(512), dim3(NT_), 0, stream, prm);
  hipLaunchKernelGGL(red_kernel, dim3(512), dim3(NT_), 0, stream, prm);
  // zero gi..wsig (contiguous state block) and the output accumulators
  hipMemsetAsync(ws + OFF_GI, 0, (size_t)2359296 * sizeof(float), stream);
  hipMemsetAsync(d_out, 0, (size_t)out_size * sizeof(float), stream);
  hipLaunchKernelGGL(a1_kernel, dim3(192), dim3(NT_), 0, stream, prm);

  constexpr int U = 3;   // unrolled steps 0..U-1 as regular kernels
  hipLaunchKernelGGL(stepB_kernel, dim3(256), dim3(NT_), 0, stream, prm, 0);
  for (int t = 1; t < U; ++t) {
    hipLaunchKernelGGL(stepA_kernel, dim3(768), dim3(NT_), 0, stream, prm, t);
    hipLaunchKernelGGL(stepB_kernel, dim3(256), dim3(NT_), 0, stream, prm, t);
  }
  int start = U;
  void* args[] = {(void*)&prm, (void*)&start};
  (void)hipLaunchCooperativeKernel((const void*)tail_kernel, dim3(384), dim3(NT_),
                                   args, 0, stream);
}

// Round 4
// 233.040 us; speedup vs baseline: 3.5412x; 1.4488x over previous
//
#include <hip/hip_runtime.h>
#include <hip/hip_cooperative_groups.h>

namespace cg = cooperative_groups;

#define DEVI static __device__ __forceinline__

typedef __attribute__((ext_vector_type(8))) short s8v;    // 8 bf16 (4 VGPR)
typedef __attribute__((ext_vector_type(4))) float f32x4;
typedef unsigned short us_t;
typedef unsigned int u32;

constexpr int NT_ = 256;
constexpr int B_ = 256, HW_ = 1024, IN_ = 512, HID_ = 1024, H3_ = 3072;
constexpr int XD_ = 1537;
constexpr int FLAT_ = 16384;

// ---- workspace layout (float offsets) ----
constexpr int OFF_WIHFBF = 0;                 // 3072*512 bf16
constexpr int OFF_WIHM2  = 393216;            // 3072*2048 bf16 (hi|lo)
constexpr int OFF_WHHBF  = 3538944;           // 3072*1024 bf16
constexpr int OFF_WIHC   = 5111808;           // 3072 f32
constexpr int OFF_CNTD   = 5114880;           // 256
constexpr int OFF_FLAGS  = 5115136;           // 128 ints
constexpr int OFF_FEATBF = 5115264;           // 256*512 bf16
constexpr int OFF_GI     = 5180800;           // 786432 f32
constexpr int OFF_GH     = 5967232;           // 786432
constexpr int OFF_H0     = 6753664;           // 262144
constexpr int OFF_H1     = 7015808;           // 262144
constexpr int OFF_WSIG   = 7277952;           // 262144 f32 (tail path)
constexpr int OFF_HHI    = 7540096;           // 256*1024 bf16
constexpr int OFF_WSIG2  = 7671168;           // 256*2048 bf16 (hi|lo)
constexpr int OFF_C2BF   = 7933312;           // 256*16384 bf16 (dead after lin)
constexpr int OFF_LINWBF = 10030464;          // 512*16384 bf16 (dead after lin)
// aliases:
constexpr int OFF_PART = OFF_GI;              // 16*256*512 f32 = 2097152 (== gi..h1)
constexpr int OFF_PA   = OFF_C2BF;            // 3*786432 f32 (fits C2BF+LINWBF)
// END = 14224768 floats = 56.9 MB

struct Params {
  const float* grid;
  const float* c1w; const float* c1b;
  const float* c2w; const float* c2b;
  const float* linw; const float* linb;
  const float* wih; const float* whh;
  const float* bih; const float* bhh;
  const float* ww;  const float* wb;
  const float* incw; const float* incb;
  const float* termw; const float* termb;
  const int* max_steps;
  float* out;   // [0:256) count, [256:262400) mask [256][1024]
  float* ws;
};

DEVI float sigm(float x) { return 1.f / (1.f + __expf(-x)); }
DEVI float tanh_(float x) { return 1.f - 2.f / (__expf(2.f * x) + 1.f); }
DEVI float2 ld2(const float* p) { return *(const float2*)p; }
DEVI void ld4(float* d, const float* p) {
  float4 v = *(const float4*)p; d[0] = v.x; d[1] = v.y; d[2] = v.z; d[3] = v.w;
}
DEVI us_t f2bf(float x) {            // RNE f32->bf16
  union { float f; u32 u; } v; v.f = x;
  u32 r = v.u + 0x7FFFu + ((v.u >> 16) & 1u);
  return (us_t)(r >> 16);
}
DEVI float bf2f(us_t h) {
  union { u32 u; float f; } v; v.u = ((u32)h) << 16; return v.f;
}
DEVI u32 pack2(float a, float b) { return (u32)f2bf(a) | ((u32)f2bf(b) << 16); }

// ---------------- conv front-end: writes bf16 c2f ----------------
__global__ __launch_bounds__(NT_) void conv_kernel(Params p) {
  __shared__ float s_in[34 * 34];
  __shared__ float s_c1[8 * 34 * 34];
  const int b = blockIdx.x;
  const int tid = threadIdx.x;
  for (int i = tid; i < 34 * 34; i += NT_) s_in[i] = 0.f;
  for (int i = tid; i < 8 * 34 * 34; i += NT_) s_c1[i] = 0.f;
  __syncthreads();
  for (int i = tid; i < 1024; i += NT_) {
    int y = i >> 5, x = i & 31;
    s_in[(y + 1) * 34 + (x + 1)] = p.grid[b * 1024 + i];
  }
  __syncthreads();
  const int pos0 = tid * 4;
  const int y = pos0 >> 5, x0 = pos0 & 31;
  {
    float win[3][6];
    #pragma unroll
    for (int dy = 0; dy < 3; ++dy)
      #pragma unroll
      for (int c = 0; c < 6; ++c) win[dy][c] = s_in[(y + dy) * 34 + x0 + c];
    float acc[8][4];
    #pragma unroll
    for (int oc = 0; oc < 8; ++oc)
      #pragma unroll
      for (int i = 0; i < 4; ++i) acc[oc][i] = p.c1b[oc];
    #pragma unroll
    for (int oc = 0; oc < 8; ++oc)
      #pragma unroll
      for (int dy = 0; dy < 3; ++dy)
        #pragma unroll
        for (int dx = 0; dx < 3; ++dx) {
          float w = p.c1w[oc * 9 + dy * 3 + dx];
          #pragma unroll
          for (int i = 0; i < 4; ++i)
            acc[oc][i] = fmaf(w, win[dy][i + dx], acc[oc][i]);
        }
    #pragma unroll
    for (int oc = 0; oc < 8; ++oc)
      #pragma unroll
      for (int i = 0; i < 4; ++i)
        s_c1[oc * 1156 + (y + 1) * 34 + (x0 + i + 1)] = fmaxf(acc[oc][i], 0.f);
  }
  __syncthreads();
  {
    float acc[16][4];
    #pragma unroll
    for (int oc = 0; oc < 16; ++oc)
      #pragma unroll
      for (int i = 0; i < 4; ++i) acc[oc][i] = p.c2b[oc];
    for (int ic = 0; ic < 8; ++ic) {
      float win[3][6];
      #pragma unroll
      for (int dy = 0; dy < 3; ++dy)
        #pragma unroll
        for (int c = 0; c < 6; ++c)
          win[dy][c] = s_c1[ic * 1156 + (y + dy) * 34 + x0 + c];
      #pragma unroll
      for (int oc = 0; oc < 16; ++oc)
        #pragma unroll
        for (int dy = 0; dy < 3; ++dy)
          #pragma unroll
          for (int dx = 0; dx < 3; ++dx) {
            float w = p.c2w[oc * 72 + ic * 9 + dy * 3 + dx];
            #pragma unroll
            for (int i = 0; i < 4; ++i)
              acc[oc][i] = fmaf(w, win[dy][i + dx], acc[oc][i]);
          }
    }
    us_t* dst = (us_t*)(p.ws + OFF_C2BF) + b * FLAT_;
    #pragma unroll
    for (int oc = 0; oc < 16; ++oc) {
      u32 lo = pack2(fmaxf(acc[oc][0], 0.f), fmaxf(acc[oc][1], 0.f));
      u32 hi = pack2(fmaxf(acc[oc][2], 0.f), fmaxf(acc[oc][3], 0.f));
      *(uint2*)(dst + oc * 1024 + pos0) = make_uint2(lo, hi);
    }
  }
}

// ---------------- prep: bf16 conversions + flags ----------------
__global__ __launch_bounds__(NT_) void prep_kernel(Params p) {
  const int gt = blockIdx.x * NT_ + threadIdx.x;
  const int gs = gridDim.x * NT_;
  us_t* wihf = (us_t*)(p.ws + OFF_WIHFBF);
  us_t* wihm2 = (us_t*)(p.ws + OFF_WIHM2);
  us_t* whhbf = (us_t*)(p.ws + OFF_WHHBF);
  us_t* linwbf = (us_t*)(p.ws + OFF_LINWBF);
  float* wihc = p.ws + OFF_WIHC;
  int* flags = (int*)(p.ws + OFF_FLAGS);
  // linw: 8.4M elems, vec4
  for (int i = gt; i < (IN_ * FLAT_) / 4; i += gs) {
    float4 v = *(const float4*)(p.linw + i * 4);
    *(uint2*)(linwbf + i * 4) = make_uint2(pack2(v.x, v.y), pack2(v.z, v.w));
  }
  // whh: 3.1M elems, vec4
  for (int i = gt; i < (H3_ * HID_) / 4; i += gs) {
    float4 v = *(const float4*)(p.whh + i * 4);
    *(uint2*)(whhbf + i * 4) = make_uint2(pack2(v.x, v.y), pack2(v.z, v.w));
  }
  // wihf: cols [0,512)
  for (int i = gt; i < H3_ * IN_; i += gs) {
    int n = i >> 9, k = i & 511;
    wihf[i] = f2bf(p.wih[n * XD_ + k]);
  }
  // wihm hi/lo: cols [512,1536)
  for (int i = gt; i < H3_ * HID_; i += gs) {
    int n = i >> 10, k = i & 1023;
    float v = p.wih[n * XD_ + 512 + k];
    us_t hi = f2bf(v);
    wihm2[n * 2048 + k] = hi;
    wihm2[n * 2048 + 1024 + k] = f2bf(v - bf2f(hi));
  }
  for (int i = gt; i < H3_; i += gs) wihc[i] = p.wih[i * XD_ + 1536];
  for (int i = gt; i < 128; i += gs) flags[i] = 1;
}

// ---- MFMA block: C[64][128] = sum_k A[m][k]*B[n][k], bf16 in, f32 out ----
// 256 threads = 4 waves; wave w owns 64x32 (n = w*32..); K = nc*64.
// LDS swizzle: 16B unit (r,u) -> slot r*8 + (u ^ (r&7)).
DEVI void mfma_block(const us_t* __restrict__ Ag, int lda,
                     const us_t* __restrict__ Bg, int ldb, int nc,
                     us_t* __restrict__ sA, us_t* __restrict__ sB,
                     float* __restrict__ dst, int ldd) {
  const int tid = threadIdx.x;
  const int ar = tid >> 3, au = tid & 7;          // stage coords
  const int sw = au ^ (ar & 7);
  const int abase = (ar * 8 + sw) * 8;            // ushort offset of 16B unit
  const us_t* a0p = Ag + (size_t)ar * lda + au * 8;
  const us_t* a1p = Ag + (size_t)(ar + 32) * lda + au * 8;
  const us_t* b0p = Bg + (size_t)ar * ldb + au * 8;
  const us_t* b1p = b0p + (size_t)32 * ldb;
  const us_t* b2p = b0p + (size_t)64 * ldb;
  const us_t* b3p = b0p + (size_t)96 * ldb;
  f32x4 acc[4][2];
  #pragma unroll
  for (int f = 0; f < 4; ++f) { acc[f][0] = (f32x4)0.f; acc[f][1] = (f32x4)0.f; }
  s8v ra0 = *(const s8v*)a0p;
  s8v ra1 = *(const s8v*)a1p;
  s8v rb0 = *(const s8v*)b0p;
  s8v rb1 = *(const s8v*)b1p;
  s8v rb2 = *(const s8v*)b2p;
  s8v rb3 = *(const s8v*)b3p;
  const int w = tid >> 6;
  const int lane = tid & 63;
  const int l15 = lane & 15, l4 = lane >> 4;
  const int rsw = l15 & 7;
  int c = 0;
  for (;;) {
    __syncthreads();
    *(s8v*)(sA + abase) = ra0;
    *(s8v*)(sA + abase + 2048) = ra1;
    *(s8v*)(sB + abase) = rb0;
    *(s8v*)(sB + abase + 2048) = rb1;
    *(s8v*)(sB + abase + 4096) = rb2;
    *(s8v*)(sB + abase + 6144) = rb3;
    ++c;
    if (c < nc) {
      const int ko = c * 64;
      ra0 = *(const s8v*)(a0p + ko);
      ra1 = *(const s8v*)(a1p + ko);
      rb0 = *(const s8v*)(b0p + ko);
      rb1 = *(const s8v*)(b1p + ko);
      rb2 = *(const s8v*)(b2p + ko);
      rb3 = *(const s8v*)(b3p + ko);
    }
    __syncthreads();
    #pragma unroll
    for (int kk = 0; kk < 2; ++kk) {
      const int uoff = ((kk * 4 + l4) ^ rsw) * 8;
      s8v bA = *(const s8v*)(sB + (w * 32 + l15) * 64 + uoff);
      s8v bB = *(const s8v*)(sB + (w * 32 + 16 + l15) * 64 + uoff);
      #pragma unroll
      for (int f = 0; f < 4; ++f) {
        s8v a = *(const s8v*)(sA + (f * 16 + l15) * 64 + uoff);
        acc[f][0] = __builtin_amdgcn_mfma_f32_16x16x32_bf16(a, bA, acc[f][0], 0, 0, 0);
        acc[f][1] = __builtin_amdgcn_mfma_f32_16x16x32_bf16(a, bB, acc[f][1], 0, 0, 0);
      }
    }
    if (c >= nc) break;
  }
  // D: row = f*16 + l4*4 + j, col = w*32 + g*16 + l15
  #pragma unroll
  for (int f = 0; f < 4; ++f)
    #pragma unroll
    for (int g = 0; g < 2; ++g) {
      float* dp = dst + (size_t)(f * 16 + l4 * 4) * ldd + w * 32 + g * 16 + l15;
      #pragma unroll
      for (int j = 0; j < 4; ++j) dp[(size_t)j * ldd] = acc[f][g][j];
    }
}

// ---------------- linear: part[ks] = c2f_bf @ linw_bf^T ----------------
__global__ __launch_bounds__(NT_) void lin_mfma(Params p) {
  __shared__ us_t sm[12288];
  const int b = blockIdx.x;                // 256 = 4mt*4nt*16ks
  const int ks = b & 15, t = b >> 4;
  const int mt = t >> 2, nt = t & 3;
  const us_t* A = (us_t*)(p.ws + OFF_C2BF) + (size_t)mt * 64 * FLAT_ + ks * 1024;
  const us_t* B = (us_t*)(p.ws + OFF_LINWBF) + (size_t)nt * 128 * FLAT_ + ks * 1024;
  float* dst = p.ws + OFF_PART + ks * (B_ * IN_) + mt * 64 * IN_ + nt * 128;
  mfma_block(A, FLAT_, B, FLAT_, 16, sm, sm + 4096, dst, IN_);
}

// ---------------- reduce split-K -> feat bf16 ----------------
__global__ __launch_bounds__(NT_) void red_kernel(Params p) {
  const int i = blockIdx.x * NT_ + threadIdx.x;   // 512 blocks exact
  const int o = i & (IN_ - 1);
  const float* part = p.ws + OFF_PART;
  float s = p.linb[o];
  #pragma unroll
  for (int ks = 0; ks < 16; ++ks) s += part[ks * (B_ * IN_) + i];
  ((us_t*)(p.ws + OFF_FEATBF))[i] = f2bf(s);
}

// ---------------- gi_base = feat @ wihf^T ----------------
__global__ __launch_bounds__(NT_) void a1_mfma(Params p) {
  __shared__ us_t sm[12288];
  const int b = blockIdx.x;                // 96 = 4mt*24nt
  const int mt = b / 24, nt = b - mt * 24;
  const us_t* A = (us_t*)(p.ws + OFF_FEATBF) + (size_t)mt * 64 * IN_;
  const us_t* B = (us_t*)(p.ws + OFF_WIHFBF) + (size_t)nt * 128 * IN_;
  float* dst = p.ws + OFF_GI + (size_t)mt * 64 * H3_ + nt * 128;
  mfma_block(A, IN_, B, IN_, 8, sm, sm + 4096, dst, H3_);
}

// ---------------- A phase MFMA: G1 partials (x3 split) + G2 direct ----------
__global__ __launch_bounds__(NT_) void stepA_mfma(Params p, int step) {
  if (((volatile int*)(p.ws + OFF_FLAGS))[step - 1]) return;
  __shared__ us_t sm[12288];
  const int b = blockIdx.x;                // 384 = 288 G1 + 96 G2
  if (b < 288) {
    const int term = b / 96, r = b - term * 96;
    const int mt = r / 24, nt = r - mt * 24;
    const us_t* A = (us_t*)(p.ws + OFF_WSIG2) + (size_t)mt * 64 * 2048 +
                    (term == 1 ? 1024 : 0);
    const us_t* B = (us_t*)(p.ws + OFF_WIHM2) + (size_t)nt * 128 * 2048 +
                    (term == 2 ? 1024 : 0);
    float* dst = p.ws + OFF_PA + (size_t)term * (B_ * H3_) + (size_t)mt * 64 * H3_ + nt * 128;
    mfma_block(A, 2048, B, 2048, 16, sm, sm + 4096, dst, H3_);
  } else {
    const int r = b - 288;
    const int mt = r / 24, nt = r - mt * 24;
    const us_t* A = (us_t*)(p.ws + OFF_HHI) + (size_t)mt * 64 * HID_;
    const us_t* B = (us_t*)(p.ws + OFF_WHHBF) + (size_t)nt * 128 * HID_;
    float* dst = p.ws + OFF_GH + (size_t)mt * 64 * H3_ + nt * 128;
    mfma_block(A, HID_, B, HID_, 16, sm, sm + 4096, dst, H3_);
  }
}

// ---------------- A epilogue: gi += pA0+pA1+pA2 + cntd (x) wihc ----------
__global__ __launch_bounds__(NT_) void stepAepi_kernel(Params p, int step) {
  if (((volatile int*)(p.ws + OFF_FLAGS))[step - 1]) return;
  const int i = (blockIdx.x * NT_ + threadIdx.x) * 4;   // 768 blocks exact
  const int m = i / H3_, n = i - m * H3_;
  const float* pA = p.ws + OFF_PA;
  float4 g = *(float4*)(p.ws + OFF_GI + i);
  float4 a0 = *(const float4*)(pA + i);
  float4 a1 = *(const float4*)(pA + (B_ * H3_) + i);
  float4 a2 = *(const float4*)(pA + 2 * (B_ * H3_) + i);
  float4 wc = *(const float4*)(p.ws + OFF_WIHC + n);
  const float cd = (p.ws + OFF_CNTD)[m];
  g.x += a0.x + a1.x + a2.x + cd * wc.x;
  g.y += a0.y + a1.y + a2.y + cd * wc.y;
  g.z += a0.z + a1.z + a2.z + cd * wc.z;
  g.w += a0.w + a1.w + a2.w + cd * wc.w;
  *(float4*)(p.ws + OFF_GI + i) = g;
}

// ---------------- B phase: fused gates + write-GEMM + dots ----------------
DEVI void b_job(const Params& p, float* sh2, float* swb,
                const float* gi, const float* gh, const float* hold,
                float* hnew, float* wsig, float* cntd, int* dflag, int job) {
  const int tid = threadIdx.x;
  const int mt = job >> 3, nt = job & 7;
  const int r0 = mt * 8, c0 = nt * 128;
  const int gr = tid >> 5;                 // 0..7
  const int gk = (tid & 31) * 2;           // 0..62
  const int wr = tid & 7;
  const int wc = (tid >> 3) * 4;           // 0..124
  const int row = r0 + gr;
  const float* giR = gi + row * H3_;
  const float* ghR = gh + row * H3_;
  const float* hR = hold + row * HID_;
  float* hW = hnew + row * HID_;
  float acc[4] = {0.f, 0.f, 0.f, 0.f};
  float incd = 0.f, termd = 0.f;
  const bool wh = (nt == 0);
  for (int kc = 0; kc < HID_; kc += 64) {
    float2 gxr = ld2(giR + kc + gk);
    float2 gxz = ld2(giR + 1024 + kc + gk);
    float2 gxn = ld2(giR + 2048 + kc + gk);
    float2 ghr = ld2(ghR + kc + gk);
    float2 ghz = ld2(ghR + 1024 + kc + gk);
    float2 ghn = ld2(ghR + 2048 + kc + gk);
    float2 hol = ld2(hR + kc + gk);
    float2 bri = ld2(p.bih + kc + gk);
    float2 brh = ld2(p.bhh + kc + gk);
    float2 bzi = ld2(p.bih + 1024 + kc + gk);
    float2 bzh = ld2(p.bhh + 1024 + kc + gk);
    float2 bni = ld2(p.bih + 2048 + kc + gk);
    float2 bnh = ld2(p.bhh + 2048 + kc + gk);
    float2 iw = ld2(p.incw + kc + gk);
    float2 tw = ld2(p.termw + kc + gk);
    float h2[2];
    {
      float rr = sigm(gxr.x + bri.x + ghr.x + brh.x);
      float zz = sigm(gxz.x + bzi.x + ghz.x + bzh.x);
      float nn = tanh_(gxn.x + bni.x + rr * (ghn.x + bnh.x));
      h2[0] = (1.f - zz) * nn + zz * hol.x;
      rr = sigm(gxr.y + bri.y + ghr.y + brh.y);
      zz = sigm(gxz.y + bzi.y + ghz.y + bzh.y);
      nn = tanh_(gxn.y + bni.y + rr * (ghn.y + bnh.y));
      h2[1] = (1.f - zz) * nn + zz * hol.y;
    }
    incd = fmaf(h2[0], iw.x, fmaf(h2[1], iw.y, incd));
    termd = fmaf(h2[0], tw.x, fmaf(h2[1], tw.y, termd));
    float4 wreg[8];
    #pragma unroll
    for (int it = 0; it < 8; ++it) {
      int id = tid + it * 256;
      int c = id >> 4, k4 = (id & 15) * 4;
      wreg[it] = *(const float4*)(p.ww + (c0 + c) * HID_ + kc + k4);
    }
    __syncthreads();
    sh2[gr * 68 + gk] = h2[0];
    sh2[gr * 68 + gk + 1] = h2[1];
    #pragma unroll
    for (int it = 0; it < 8; ++it) {
      int id = tid + it * 256;
      int c = id >> 4, k4 = (id & 15) * 4;
      swb[(k4 + 0) * 132 + c] = wreg[it].x;
      swb[(k4 + 1) * 132 + c] = wreg[it].y;
      swb[(k4 + 2) * 132 + c] = wreg[it].z;
      swb[(k4 + 3) * 132 + c] = wreg[it].w;
    }
    if (wh) {
      *(float2*)(hW + kc + gk) = make_float2(h2[0], h2[1]);
      *(u32*)((us_t*)(p.ws + OFF_HHI) + row * HID_ + kc + gk) = pack2(h2[0], h2[1]);
    }
    __syncthreads();
    #pragma unroll 8
    for (int kk = 0; kk < 64; ++kk) {
      float a = sh2[wr * 68 + kk];
      float4 b = *(const float4*)(swb + kk * 132 + wc);
      acc[0] = fmaf(a, b.x, acc[0]);
      acc[1] = fmaf(a, b.y, acc[1]);
      acc[2] = fmaf(a, b.z, acc[2]);
      acc[3] = fmaf(a, b.w, acc[3]);
    }
  }
  if (wh) {
    #pragma unroll
    for (int off = 16; off > 0; off >>= 1) {
      incd += __shfl_down(incd, off, 32);
      termd += __shfl_down(termd, off, 32);
    }
    if ((tid & 31) == 0) {
      float cd = sigm(incd + p.incb[0]);
      cntd[row] = cd;
      p.out[row] += cd;
      if (termd + p.termb[0] <= 0.f) atomicAnd(dflag, 0);
    }
  }
  {
    const int m = r0 + wr;
    float4 wb4 = *(const float4*)(p.wb + c0 + wc);
    float4 sv = {sigm(acc[0] + wb4.x), sigm(acc[1] + wb4.y),
                 sigm(acc[2] + wb4.z), sigm(acc[3] + wb4.w)};
    float* op = p.out + B_ + m * HW_ + c0 + wc;
    float4 ov = *(float4*)op;
    ov.x += sv.x; ov.y += sv.y; ov.z += sv.z; ov.w += sv.w;
    *(float4*)op = ov;
    *(float4*)(wsig + m * HID_ + c0 + wc) = sv;
    // bf16 hi/lo for next step's MFMA A-phase
    us_t* w2 = (us_t*)(p.ws + OFF_WSIG2) + m * 2048 + c0 + wc;
    us_t h0 = f2bf(sv.x), h1 = f2bf(sv.y), h2b = f2bf(sv.z), h3 = f2bf(sv.w);
    *(uint2*)w2 = make_uint2((u32)h0 | ((u32)h1 << 16), (u32)h2b | ((u32)h3 << 16));
    *(uint2*)(w2 + 1024) = make_uint2(
        pack2(sv.x - bf2f(h0), sv.y - bf2f(h1)),
        pack2(sv.z - bf2f(h2b), sv.w - bf2f(h3)));
  }
}

// ---------------- B phase as regular kernel: 256 jobs ----------------
__global__ __launch_bounds__(NT_, 2) void stepB_kernel(Params p, int step) {
  int* flags = (int*)(p.ws + OFF_FLAGS);
  if (step > 0 && ((volatile int*)flags)[step - 1]) return;
  __shared__ __align__(16) float smem[8992];
  float* sh2 = smem;
  float* swb = smem + 544;
  float* hcur = p.ws + ((step & 1) ? OFF_H1 : OFF_H0);
  float* hnxt = p.ws + ((step & 1) ? OFF_H0 : OFF_H1);
  b_job(p, sh2, swb, p.ws + OFF_GI, p.ws + OFF_GH, hcur, hnxt,
        p.ws + OFF_WSIG, p.ws + OFF_CNTD, &flags[step], blockIdx.x);
}

// ---- f32 double-buffered 64x64 GEMM tile (tail fallback); SB = scalar B loads ----
template <bool SB>
DEVI void gemm_db64(const float* __restrict__ A, int lda,
                    const float* __restrict__ Bw, int ldb, int K,
                    float* __restrict__ As, float* __restrict__ Bs,
                    float (&acc)[4][4]) {
  constexpr int P = 68;
  const int tid = threadIdx.x;
  const int tx = tid & 15, ty = tid >> 4;
  const int lr = tid >> 2, lk = (tid & 3) << 2;
  #pragma unroll
  for (int i = 0; i < 4; ++i)
    #pragma unroll
    for (int j = 0; j < 4; ++j) acc[i][j] = 0.f;
  auto ldb4 = [&](int k0) {
    float4 v;
    if constexpr (SB) {
      const float* q = Bw + (size_t)lr * ldb + k0 + lk;
      v.x = q[0]; v.y = q[1]; v.z = q[2]; v.w = q[3];
    } else {
      v = *(const float4*)(Bw + (size_t)lr * ldb + k0 + lk);
    }
    return v;
  };
  float4 va = *(const float4*)(A + lr * lda + lk);
  float4 vb = ldb4(0);
  As[(lk + 0) * P + lr] = va.x; As[(lk + 1) * P + lr] = va.y;
  As[(lk + 2) * P + lr] = va.z; As[(lk + 3) * P + lr] = va.w;
  Bs[(lk + 0) * P + lr] = vb.x; Bs[(lk + 1) * P + lr] = vb.y;
  Bs[(lk + 2) * P + lr] = vb.z; Bs[(lk + 3) * P + lr] = vb.w;
  __syncthreads();
  int cur = 0;
  for (int k0 = 16; k0 < K; k0 += 16) {
    va = *(const float4*)(A + lr * lda + k0 + lk);
    vb = ldb4(k0);
    const float* as = As + cur * (16 * P);
    const float* bs = Bs + cur * (16 * P);
    #pragma unroll
    for (int kk = 0; kk < 16; ++kk) {
      float a[4], b[4];
      ld4(a, as + kk * P + ty * 4);
      ld4(b, bs + kk * P + tx * 4);
      #pragma unroll
      for (int i = 0; i < 4; ++i)
        #pragma unroll
        for (int j = 0; j < 4; ++j) acc[i][j] = fmaf(a[i], b[j], acc[i][j]);
    }
    __syncthreads();
    float* asw = As + (cur ^ 1) * (16 * P);
    float* bsw = Bs + (cur ^ 1) * (16 * P);
    asw[(lk + 0) * P + lr] = va.x; asw[(lk + 1) * P + lr] = va.y;
    asw[(lk + 2) * P + lr] = va.z; asw[(lk + 3) * P + lr] = va.w;
    bsw[(lk + 0) * P + lr] = vb.x; bsw[(lk + 1) * P + lr] = vb.y;
    bsw[(lk + 2) * P + lr] = vb.z; bsw[(lk + 3) * P + lr] = vb.w;
    __syncthreads();
    cur ^= 1;
  }
  const float* as = As + cur * (16 * P);
  const float* bs = Bs + cur * (16 * P);
  #pragma unroll
  for (int kk = 0; kk < 16; ++kk) {
    float a[4], b[4];
    ld4(a, as + kk * P + ty * 4);
    ld4(b, bs + kk * P + tx * 4);
    #pragma unroll
    for (int i = 0; i < 4; ++i)
      #pragma unroll
      for (int j = 0; j < 4; ++j) acc[i][j] = fmaf(a[i], b[j], acc[i][j]);
  }
}

// ---------------- cooperative tail (steps >= start; usually exits) ----------
__global__ __launch_bounds__(NT_, 2) void tail_kernel(Params p, int start) {
  int* flags = (int*)(p.ws + OFF_FLAGS);
  if (((volatile int*)flags)[start - 1]) return;
  cg::grid_group gg = cg::this_grid();
  __shared__ __align__(16) float smem[8992];
  float* As = smem;
  float* Bs = smem + 2176;
  float* sh2 = smem;
  float* swb = smem + 544;
  float* const ws = p.ws;
  float* const gi = ws + OFF_GI;
  float* const gh = ws + OFF_GH;
  float* const wsig = ws + OFF_WSIG;
  float* const cntd = ws + OFF_CNTD;
  const float* const wihc = ws + OFF_WIHC;
  const int tid = threadIdx.x;
  const int bid = blockIdx.x;
  const int nb = gridDim.x;
  const int tx = tid & 15, ty = tid >> 4;
  const int msteps = p.max_steps[0];

  for (int step = start; step < msteps; ++step) {
    float* hcur = ws + ((step & 1) ? OFF_H1 : OFF_H0);
    float* hnxt = ws + ((step & 1) ? OFF_H0 : OFF_H1);
    for (int job = bid; job < 384; job += nb) {
      float acc[4][4];
      if (job < 192) {
        const int mt = job / 48, nt = job - mt * 48;
        gemm_db64<true>(wsig + mt * 64 * HID_, HID_,
                        p.wih + (size_t)nt * 64 * XD_ + 512, XD_, HID_, As, Bs, acc);
        #pragma unroll
        for (int i = 0; i < 4; ++i) {
          const int m = mt * 64 + ty * 4 + i;
          const float cd = cntd[m];
          float4 wc4 = *(const float4*)(wihc + nt * 64 + tx * 4);
          float* gp = gi + m * H3_ + nt * 64 + tx * 4;
          float4 g = *(float4*)gp;
          g.x += acc[i][0] + cd * wc4.x;
          g.y += acc[i][1] + cd * wc4.y;
          g.z += acc[i][2] + cd * wc4.z;
          g.w += acc[i][3] + cd * wc4.w;
          *(float4*)gp = g;
        }
      } else {
        const int j = job - 192;
        const int mt = j / 48, nt = j - mt * 48;
        gemm_db64<false>(hcur + mt * 64 * HID_, HID_,
                         p.whh + (size_t)nt * 64 * HID_, HID_, HID_, As, Bs, acc);
        #pragma unroll
        for (int i = 0; i < 4; ++i) {
          float4 v = {acc[i][0], acc[i][1], acc[i][2], acc[i][3]};
          *(float4*)(gh + (mt * 64 + ty * 4 + i) * H3_ + nt * 64 + tx * 4) = v;
        }
      }
      __syncthreads();
    }
    gg.sync();
    for (int job = bid; job < 256; job += nb)
      b_job(p, sh2, swb, gi, gh, hcur, hnxt, wsig, cntd, &flags[step], job);
    gg.sync();
    if (((volatile int*)flags)[step]) break;
  }
}

extern "C" void kernel_launch(void* const* d_in, const int* in_sizes, int n_in,
                              void* d_out, int out_size, void* d_ws, size_t ws_size,
                              hipStream_t stream) {
  (void)in_sizes; (void)n_in; (void)ws_size;
  Params prm;
  prm.grid = (const float*)d_in[0];
  prm.c1w  = (const float*)d_in[1];
  prm.c1b  = (const float*)d_in[2];
  prm.c2w  = (const float*)d_in[3];
  prm.c2b  = (const float*)d_in[4];
  prm.linw = (const float*)d_in[5];
  prm.linb = (const float*)d_in[6];
  prm.wih  = (const float*)d_in[7];
  prm.whh  = (const float*)d_in[8];
  prm.bih  = (const float*)d_in[9];
  prm.bhh  = (const float*)d_in[10];
  prm.ww   = (const float*)d_in[11];
  prm.wb   = (const float*)d_in[12];
  prm.incw = (const float*)d_in[13];
  prm.incb = (const float*)d_in[14];
  prm.termw = (const float*)d_in[15];
  prm.termb = (const float*)d_in[16];
  prm.max_steps = (const int*)d_in[17];
  prm.out = (float*)d_out;
  prm.ws = (float*)d_ws;
  float* ws = (float*)d_ws;

  hipLaunchKernelGGL(conv_kernel, dim3(B_), dim3(NT_), 0, stream, prm);
  hipLaunchKernelGGL(prep_kernel, dim3(2048), dim3(NT_), 0, stream, prm);
  hipLaunchKernelGGL(lin_mfma, dim3(256), dim3(NT_), 0, stream, prm);
  hipLaunchKernelGGL(red_kernel, dim3(512), dim3(NT_), 0, stream, prm);
  // state zeroing AFTER red (part aliases gi..h1)
  hipMemsetAsync(ws + OFF_GH, 0, (size_t)786432 * sizeof(float), stream);
  hipMemsetAsync(ws + OFF_H0, 0, (size_t)262144 * sizeof(float), stream);
  hipMemsetAsync(d_out, 0, (size_t)out_size * sizeof(float), stream);
  hipLaunchKernelGGL(a1_mfma, dim3(96), dim3(NT_), 0, stream, prm);

  constexpr int U = 3;
  hipLaunchKernelGGL(stepB_kernel, dim3(256), dim3(NT_), 0, stream, prm, 0);
  for (int t = 1; t < U; ++t) {
    hipLaunchKernelGGL(stepA_mfma, dim3(384), dim3(NT_), 0, stream, prm, t);
    hipLaunchKernelGGL(stepAepi_kernel, dim3(768), dim3(NT_), 0, stream, prm, t);
    hipLaunchKernelGGL(stepB_kernel, dim3(256), dim3(NT_), 0, stream, prm, t);
  }
  int start = U;
  void* args[] = {(void*)&prm, (void*)&start};
  (void)hipLaunchCooperativeKernel((const void*)tail_kernel, dim3(384), dim3(NT_),
                                   args, 0, stream);
}

// Round 5
// 155.524 us; speedup vs baseline: 5.3061x; 1.4984x over previous
//
#include <hip/hip_runtime.h>
#include <hip/hip_cooperative_groups.h>

namespace cg = cooperative_groups;

#define DEVI static __device__ __forceinline__

typedef __attribute__((ext_vector_type(8))) short s8v;    // 8 bf16 (4 VGPR)
typedef __attribute__((ext_vector_type(4))) float f32x4;
typedef unsigned short us_t;
typedef unsigned int u32;

constexpr int NT_ = 256;
constexpr int B_ = 256, HW_ = 1024, IN_ = 512, HID_ = 1024, H3_ = 3072;
constexpr int XD_ = 1537;
constexpr int FLAT_ = 16384;

// ---- workspace layout (float offsets) ----
constexpr int OFF_WIHFBF = 0;                 // 3072*512 bf16
constexpr int OFF_WIHM2  = 393216;            // 3072*2048 bf16 (hi|lo)
constexpr int OFF_WHHBF  = 3538944;           // 3072*1024 bf16
constexpr int OFF_WIHC   = 5111808;           // 3072 f32
constexpr int OFF_CNTD   = 5114880;           // 256
constexpr int OFF_FLAGS  = 5115136;           // 128 ints
constexpr int OFF_FEATBF = 5115264;           // 256*512 bf16
constexpr int OFF_GI     = 5180800;           // 786432 f32
constexpr int OFF_GH     = 5967232;           // 786432
constexpr int OFF_H0     = 6753664;           // 262144
constexpr int OFF_H1     = 7015808;           // 262144
constexpr int OFF_WSIG   = 7277952;           // 262144 f32 (tail path)
constexpr int OFF_HHI    = 7540096;           // 256*1024 bf16
constexpr int OFF_WSIG2  = 7671168;           // 256*2048 bf16 (hi|lo)
constexpr int OFF_C2BF   = 7933312;           // 256*16384 bf16 (dead after lin)
constexpr int OFF_LINWBF = 10030464;          // 512*16384 bf16 (dead after lin)
// aliases:
constexpr int OFF_PART = OFF_GI;              // lin split-K partials (16*131072)
constexpr int OFF_PA   = OFF_C2BF;            // stepA partials 3*786432 / stepW partials 8*262144
constexpr int OFF_WWBF = 10292608;            // 1024*1024 bf16 = 262144 f32-slots, at PA end,
                                              //   inside dead linwbf; written by red (after lin)
// END = 14224768 floats = 56.9 MB

struct Params {
  const float* grid;
  const float* c1w; const float* c1b;
  const float* c2w; const float* c2b;
  const float* linw; const float* linb;
  const float* wih; const float* whh;
  const float* bih; const float* bhh;
  const float* ww;  const float* wb;
  const float* incw; const float* incb;
  const float* termw; const float* termb;
  const int* max_steps;
  float* out;   // [0:256) count, [256:262400) mask [256][1024]
  float* ws;
};

DEVI float sigm(float x) { return 1.f / (1.f + __expf(-x)); }
DEVI float tanh_(float x) { return 1.f - 2.f / (__expf(2.f * x) + 1.f); }
DEVI float2 ld2(const float* p) { return *(const float2*)p; }
DEVI void ld4(float* d, const float* p) {
  float4 v = *(const float4*)p; d[0] = v.x; d[1] = v.y; d[2] = v.z; d[3] = v.w;
}
DEVI us_t f2bf(float x) {            // RNE f32->bf16
  union { float f; u32 u; } v; v.f = x;
  u32 r = v.u + 0x7FFFu + ((v.u >> 16) & 1u);
  return (us_t)(r >> 16);
}
DEVI float bf2f(us_t h) {
  union { u32 u; float f; } v; v.u = ((u32)h) << 16; return v.f;
}
DEVI u32 pack2(float a, float b) { return (u32)f2bf(a) | ((u32)f2bf(b) << 16); }

// ---------------- conv front-end: writes bf16 c2f ----------------
__global__ __launch_bounds__(NT_) void conv_kernel(Params p) {
  __shared__ float s_in[34 * 34];
  __shared__ float s_c1[8 * 34 * 34];
  const int b = blockIdx.x;
  const int tid = threadIdx.x;
  for (int i = tid; i < 34 * 34; i += NT_) s_in[i] = 0.f;
  for (int i = tid; i < 8 * 34 * 34; i += NT_) s_c1[i] = 0.f;
  __syncthreads();
  for (int i = tid; i < 1024; i += NT_) {
    int y = i >> 5, x = i & 31;
    s_in[(y + 1) * 34 + (x + 1)] = p.grid[b * 1024 + i];
  }
  __syncthreads();
  const int pos0 = tid * 4;
  const int y = pos0 >> 5, x0 = pos0 & 31;
  {
    float win[3][6];
    #pragma unroll
    for (int dy = 0; dy < 3; ++dy)
      #pragma unroll
      for (int c = 0; c < 6; ++c) win[dy][c] = s_in[(y + dy) * 34 + x0 + c];
    float acc[8][4];
    #pragma unroll
    for (int oc = 0; oc < 8; ++oc)
      #pragma unroll
      for (int i = 0; i < 4; ++i) acc[oc][i] = p.c1b[oc];
    #pragma unroll
    for (int oc = 0; oc < 8; ++oc)
      #pragma unroll
      for (int dy = 0; dy < 3; ++dy)
        #pragma unroll
        for (int dx = 0; dx < 3; ++dx) {
          float w = p.c1w[oc * 9 + dy * 3 + dx];
          #pragma unroll
          for (int i = 0; i < 4; ++i)
            acc[oc][i] = fmaf(w, win[dy][i + dx], acc[oc][i]);
        }
    #pragma unroll
    for (int oc = 0; oc < 8; ++oc)
      #pragma unroll
      for (int i = 0; i < 4; ++i)
        s_c1[oc * 1156 + (y + 1) * 34 + (x0 + i + 1)] = fmaxf(acc[oc][i], 0.f);
  }
  __syncthreads();
  {
    float acc[16][4];
    #pragma unroll
    for (int oc = 0; oc < 16; ++oc)
      #pragma unroll
      for (int i = 0; i < 4; ++i) acc[oc][i] = p.c2b[oc];
    for (int ic = 0; ic < 8; ++ic) {
      float win[3][6];
      #pragma unroll
      for (int dy = 0; dy < 3; ++dy)
        #pragma unroll
        for (int c = 0; c < 6; ++c)
          win[dy][c] = s_c1[ic * 1156 + (y + dy) * 34 + x0 + c];
      #pragma unroll
      for (int oc = 0; oc < 16; ++oc)
        #pragma unroll
        for (int dy = 0; dy < 3; ++dy)
          #pragma unroll
          for (int dx = 0; dx < 3; ++dx) {
            float w = p.c2w[oc * 72 + ic * 9 + dy * 3 + dx];
            #pragma unroll
            for (int i = 0; i < 4; ++i)
              acc[oc][i] = fmaf(w, win[dy][i + dx], acc[oc][i]);
          }
    }
    us_t* dst = (us_t*)(p.ws + OFF_C2BF) + b * FLAT_;
    #pragma unroll
    for (int oc = 0; oc < 16; ++oc) {
      u32 lo = pack2(fmaxf(acc[oc][0], 0.f), fmaxf(acc[oc][1], 0.f));
      u32 hi = pack2(fmaxf(acc[oc][2], 0.f), fmaxf(acc[oc][3], 0.f));
      *(uint2*)(dst + oc * 1024 + pos0) = make_uint2(lo, hi);
    }
  }
}

// ---------------- prep: bf16 conversions + flags ----------------
__global__ __launch_bounds__(NT_) void prep_kernel(Params p) {
  const int gt = blockIdx.x * NT_ + threadIdx.x;
  const int gs = gridDim.x * NT_;
  us_t* wihf = (us_t*)(p.ws + OFF_WIHFBF);
  us_t* wihm2 = (us_t*)(p.ws + OFF_WIHM2);
  us_t* whhbf = (us_t*)(p.ws + OFF_WHHBF);
  us_t* linwbf = (us_t*)(p.ws + OFF_LINWBF);
  float* wihc = p.ws + OFF_WIHC;
  int* flags = (int*)(p.ws + OFF_FLAGS);
  for (int i = gt; i < (IN_ * FLAT_) / 4; i += gs) {
    float4 v = *(const float4*)(p.linw + (size_t)i * 4);
    *(uint2*)(linwbf + (size_t)i * 4) = make_uint2(pack2(v.x, v.y), pack2(v.z, v.w));
  }
  for (int i = gt; i < (H3_ * HID_) / 4; i += gs) {
    float4 v = *(const float4*)(p.whh + (size_t)i * 4);
    *(uint2*)(whhbf + (size_t)i * 4) = make_uint2(pack2(v.x, v.y), pack2(v.z, v.w));
  }
  for (int i = gt; i < H3_ * IN_; i += gs) {
    int n = i >> 9, k = i & 511;
    wihf[i] = f2bf(p.wih[n * XD_ + k]);
  }
  for (int i = gt; i < H3_ * HID_; i += gs) {
    int n = i >> 10, k = i & 1023;
    float v = p.wih[n * XD_ + 512 + k];
    us_t hi = f2bf(v);
    wihm2[n * 2048 + k] = hi;
    wihm2[n * 2048 + 1024 + k] = f2bf(v - bf2f(hi));
  }
  for (int i = gt; i < H3_; i += gs) wihc[i] = p.wih[i * XD_ + 1536];
  for (int i = gt; i < 128; i += gs) flags[i] = 1;
}

// ---- MFMA block: C[64][128] = sum_k A[m][k]*B[n][k], bf16 in, f32 out ----
// 256 threads = 4 waves; wave w owns 64x32; K = nc*64.
// LDS swizzle: 16B unit (r,u) -> slot r*8 + (u ^ (r&7)).
DEVI void mfma_block(const us_t* __restrict__ Ag, int lda,
                     const us_t* __restrict__ Bg, int ldb, int nc,
                     us_t* __restrict__ sA, us_t* __restrict__ sB,
                     float* __restrict__ dst, int ldd) {
  const int tid = threadIdx.x;
  const int ar = tid >> 3, au = tid & 7;
  const int sw = au ^ (ar & 7);
  const int abase = (ar * 8 + sw) * 8;
  const us_t* a0p = Ag + (size_t)ar * lda + au * 8;
  const us_t* a1p = Ag + (size_t)(ar + 32) * lda + au * 8;
  const us_t* b0p = Bg + (size_t)ar * ldb + au * 8;
  const us_t* b1p = b0p + (size_t)32 * ldb;
  const us_t* b2p = b0p + (size_t)64 * ldb;
  const us_t* b3p = b0p + (size_t)96 * ldb;
  f32x4 acc[4][2];
  #pragma unroll
  for (int f = 0; f < 4; ++f) { acc[f][0] = (f32x4)0.f; acc[f][1] = (f32x4)0.f; }
  s8v ra0 = *(const s8v*)a0p;
  s8v ra1 = *(const s8v*)a1p;
  s8v rb0 = *(const s8v*)b0p;
  s8v rb1 = *(const s8v*)b1p;
  s8v rb2 = *(const s8v*)b2p;
  s8v rb3 = *(const s8v*)b3p;
  const int w = tid >> 6;
  const int lane = tid & 63;
  const int l15 = lane & 15, l4 = lane >> 4;
  const int rsw = l15 & 7;
  int c = 0;
  for (;;) {
    __syncthreads();
    *(s8v*)(sA + abase) = ra0;
    *(s8v*)(sA + abase + 2048) = ra1;
    *(s8v*)(sB + abase) = rb0;
    *(s8v*)(sB + abase + 2048) = rb1;
    *(s8v*)(sB + abase + 4096) = rb2;
    *(s8v*)(sB + abase + 6144) = rb3;
    ++c;
    if (c < nc) {
      const int ko = c * 64;
      ra0 = *(const s8v*)(a0p + ko);
      ra1 = *(const s8v*)(a1p + ko);
      rb0 = *(const s8v*)(b0p + ko);
      rb1 = *(const s8v*)(b1p + ko);
      rb2 = *(const s8v*)(b2p + ko);
      rb3 = *(const s8v*)(b3p + ko);
    }
    __syncthreads();
    #pragma unroll
    for (int kk = 0; kk < 2; ++kk) {
      const int uoff = ((kk * 4 + l4) ^ rsw) * 8;
      s8v bA = *(const s8v*)(sB + (w * 32 + l15) * 64 + uoff);
      s8v bB = *(const s8v*)(sB + (w * 32 + 16 + l15) * 64 + uoff);
      #pragma unroll
      for (int f = 0; f < 4; ++f) {
        s8v a = *(const s8v*)(sA + (f * 16 + l15) * 64 + uoff);
        acc[f][0] = __builtin_amdgcn_mfma_f32_16x16x32_bf16(a, bA, acc[f][0], 0, 0, 0);
        acc[f][1] = __builtin_amdgcn_mfma_f32_16x16x32_bf16(a, bB, acc[f][1], 0, 0, 0);
      }
    }
    if (c >= nc) break;
  }
  #pragma unroll
  for (int f = 0; f < 4; ++f)
    #pragma unroll
    for (int g = 0; g < 2; ++g) {
      float* dp = dst + (size_t)(f * 16 + l4 * 4) * ldd + w * 32 + g * 16 + l15;
      #pragma unroll
      for (int j = 0; j < 4; ++j) dp[(size_t)j * ldd] = acc[f][g][j];
    }
}

// ---------------- linear: part[ks] = c2f_bf @ linw_bf^T ----------------
__global__ __launch_bounds__(NT_) void lin_mfma(Params p) {
  __shared__ us_t sm[12288];
  const int b = blockIdx.x;                // 256 = 16ks x 4mt x 4nt
  const int ks = b & 15, t = b >> 4;
  const int mt = t >> 2, nt = t & 3;
  const us_t* A = (us_t*)(p.ws + OFF_C2BF) + (size_t)mt * 64 * FLAT_ + ks * 1024;
  const us_t* B = (us_t*)(p.ws + OFF_LINWBF) + (size_t)nt * 128 * FLAT_ + ks * 1024;
  float* dst = p.ws + OFF_PART + ks * (B_ * IN_) + mt * 64 * IN_ + nt * 128;
  mfma_block(A, FLAT_, B, FLAT_, 16, sm, sm + 4096, dst, IN_);
}

// ------------- reduce split-K -> feat bf16; also convert ww -> bf16 -------------
__global__ __launch_bounds__(NT_) void red_kernel(Params p) {
  const int gt = blockIdx.x * NT_ + threadIdx.x;   // 512 blocks, 131072 threads
  {
    const int o = gt & (IN_ - 1);
    const float* part = p.ws + OFF_PART;
    float s = p.linb[o];
    #pragma unroll
    for (int ks = 0; ks < 16; ++ks) s += part[ks * (B_ * IN_) + gt];
    ((us_t*)(p.ws + OFF_FEATBF))[gt] = f2bf(s);
  }
  us_t* wwbf = (us_t*)(p.ws + OFF_WWBF);
  #pragma unroll
  for (int r = 0; r < 2; ++r) {
    const int j = gt + r * 131072;                 // 262144 float4 units total
    float4 v = *(const float4*)(p.ww + (size_t)j * 4);
    *(uint2*)(wwbf + (size_t)j * 4) = make_uint2(pack2(v.x, v.y), pack2(v.z, v.w));
  }
}

// ---------------- gi_base = feat @ wihf^T ----------------
__global__ __launch_bounds__(NT_) void a1_mfma(Params p) {
  __shared__ us_t sm[12288];
  const int b = blockIdx.x;                // 96 = 4mt*24nt
  const int mt = b / 24, nt = b - mt * 24;
  const us_t* A = (us_t*)(p.ws + OFF_FEATBF) + (size_t)mt * 64 * IN_;
  const us_t* B = (us_t*)(p.ws + OFF_WIHFBF) + (size_t)nt * 128 * IN_;
  float* dst = p.ws + OFF_GI + (size_t)mt * 64 * H3_ + nt * 128;
  mfma_block(A, IN_, B, IN_, 8, sm, sm + 4096, dst, H3_);
}

// ---------------- A phase MFMA: G1 partials (x3 split) + G2 direct ----------
__global__ __launch_bounds__(NT_) void stepA_mfma(Params p, int step) {
  if (((volatile int*)(p.ws + OFF_FLAGS))[step - 1]) return;
  __shared__ us_t sm[12288];
  const int b = blockIdx.x;                // 384 = 288 G1 + 96 G2
  if (b < 288) {
    const int term = b / 96, r = b - term * 96;
    const int mt = r / 24, nt = r - mt * 24;
    const us_t* A = (us_t*)(p.ws + OFF_WSIG2) + (size_t)mt * 64 * 2048 +
                    (term == 1 ? 1024 : 0);
    const us_t* B = (us_t*)(p.ws + OFF_WIHM2) + (size_t)nt * 128 * 2048 +
                    (term == 2 ? 1024 : 0);
    float* dst = p.ws + OFF_PA + (size_t)term * (B_ * H3_) + (size_t)mt * 64 * H3_ + nt * 128;
    mfma_block(A, 2048, B, 2048, 16, sm, sm + 4096, dst, H3_);
  } else {
    const int r = b - 288;
    const int mt = r / 24, nt = r - mt * 24;
    const us_t* A = (us_t*)(p.ws + OFF_HHI) + (size_t)mt * 64 * HID_;
    const us_t* B = (us_t*)(p.ws + OFF_WHHBF) + (size_t)nt * 128 * HID_;
    float* dst = p.ws + OFF_GH + (size_t)mt * 64 * H3_ + nt * 128;
    mfma_block(A, HID_, B, HID_, 16, sm, sm + 4096, dst, H3_);
  }
}

// ---- stepG: fold A-partials into gi, gates ONCE per row, dots, count/flag ----
// one block per row (256 blocks x 256 threads), thread covers cols tid+q*256
__global__ __launch_bounds__(NT_) void stepG_kernel(Params p, int step) {
  int* flags = (int*)(p.ws + OFF_FLAGS);
  if (step > 0 && ((volatile int*)flags)[step - 1]) return;
  __shared__ float sred[8];
  const int row = blockIdx.x;
  const int tid = threadIdx.x;
  const size_t base = (size_t)row * H3_;
  float* const gi = p.ws + OFF_GI + base;
  const float* const gh = p.ws + OFF_GH + base;
  const float* const pA = p.ws + OFF_PA;
  const float* const wihc = p.ws + OFF_WIHC;
  const float* hold = p.ws + ((step & 1) ? OFF_H1 : OFF_H0) + (size_t)row * HID_;
  float* hnew = p.ws + ((step & 1) ? OFF_H0 : OFF_H1) + (size_t)row * HID_;
  us_t* hhi = (us_t*)(p.ws + OFF_HHI) + (size_t)row * HID_;
  const float cd = (step > 0) ? (p.ws + OFF_CNTD)[row] : 0.f;
  float incd = 0.f, termd = 0.f;
  #pragma unroll
  for (int q = 0; q < 4; ++q) {
    const int c = tid + q * NT_;
    float gr_ = gi[c], gz_ = gi[1024 + c], gn_ = gi[2048 + c];
    float hr_ = 0.f, hz_ = 0.f, hn_ = 0.f, hv = 0.f;
    if (step > 0) {
      gr_ += pA[base + c] + pA[786432 + base + c] + pA[1572864 + base + c] +
             cd * wihc[c];
      gz_ += pA[base + 1024 + c] + pA[786432 + base + 1024 + c] +
             pA[1572864 + base + 1024 + c] + cd * wihc[1024 + c];
      gn_ += pA[base + 2048 + c] + pA[786432 + base + 2048 + c] +
             pA[1572864 + base + 2048 + c] + cd * wihc[2048 + c];
      gi[c] = gr_; gi[1024 + c] = gz_; gi[2048 + c] = gn_;   // materialize for tail
      hr_ = gh[c]; hz_ = gh[1024 + c]; hn_ = gh[2048 + c];
      hv = hold[c];
    }
    float rr = sigm(gr_ + p.bih[c] + hr_ + p.bhh[c]);
    float zz = sigm(gz_ + p.bih[1024 + c] + hz_ + p.bhh[1024 + c]);
    float nn = tanh_(gn_ + p.bih[2048 + c] + rr * (hn_ + p.bhh[2048 + c]));
    float h2 = (1.f - zz) * nn + zz * hv;
    hnew[c] = h2;
    hhi[c] = f2bf(h2);
    incd = fmaf(h2, p.incw[c], incd);
    termd = fmaf(h2, p.termw[c], termd);
  }
  #pragma unroll
  for (int off = 32; off > 0; off >>= 1) {
    incd += __shfl_down(incd, off);
    termd += __shfl_down(termd, off);
  }
  if ((tid & 63) == 0) { sred[tid >> 6] = incd; sred[4 + (tid >> 6)] = termd; }
  __syncthreads();
  if (tid == 0) {
    float it = sred[0] + sred[1] + sred[2] + sred[3];
    float tt = sred[4] + sred[5] + sred[6] + sred[7];
    float cdn = sigm(it + p.incb[0]);
    (p.ws + OFF_CNTD)[row] = cdn;
    p.out[row] += cdn;
    if (tt + p.termb[0] <= 0.f) atomicAnd(&flags[step], 0);
  }
}

// ---------------- stepW: write-GEMM partials via MFMA, split-K=8 ----------------
__global__ __launch_bounds__(NT_) void stepW_mfma(Params p, int step) {
  if (step > 0 && ((volatile int*)(p.ws + OFF_FLAGS))[step - 1]) return;
  __shared__ us_t sm[12288];
  const int b = blockIdx.x;           // 256 = 8ks x 4mt x 8nt
  const int ks = b & 7, t = b >> 3;
  const int mt = t >> 3, nt = t & 7;
  const us_t* A = (us_t*)(p.ws + OFF_HHI) + (size_t)mt * 64 * HID_ + ks * 128;
  const us_t* B = (us_t*)(p.ws + OFF_WWBF) + (size_t)nt * 128 * HID_ + ks * 128;
  float* dst = p.ws + OFF_PA + ks * (B_ * HW_) + (size_t)mt * 64 * HW_ + nt * 128;
  mfma_block(A, HID_, B, HID_, 2, sm, sm + 4096, dst, HW_);
}

// ------- stepWepi: reduce partials, sigmoid, mask accum, wsig/wsig2 emit -------
__global__ __launch_bounds__(NT_) void stepWepi_kernel(Params p, int step) {
  if (step > 0 && ((volatile int*)(p.ws + OFF_FLAGS))[step - 1]) return;
  const int i = (blockIdx.x * NT_ + threadIdx.x) * 4;   // 256 blocks exact
  const int m = i >> 10, n = i & 1023;
  const float* pW = p.ws + OFF_PA;
  float4 s = *(const float4*)(p.wb + n);
  #pragma unroll
  for (int ks = 0; ks < 8; ++ks) {
    float4 v = *(const float4*)(pW + ks * (B_ * HW_) + i);
    s.x += v.x; s.y += v.y; s.z += v.z; s.w += v.w;
  }
  float4 sv = {sigm(s.x), sigm(s.y), sigm(s.z), sigm(s.w)};
  float* op = p.out + B_ + i;
  float4 ov = *(float4*)op;
  ov.x += sv.x; ov.y += sv.y; ov.z += sv.z; ov.w += sv.w;
  *(float4*)op = ov;
  *(float4*)(p.ws + OFF_WSIG + i) = sv;
  us_t* w2 = (us_t*)(p.ws + OFF_WSIG2) + (size_t)m * 2048 + n;
  us_t h0 = f2bf(sv.x), h1 = f2bf(sv.y), h2b = f2bf(sv.z), h3 = f2bf(sv.w);
  *(uint2*)w2 = make_uint2((u32)h0 | ((u32)h1 << 16), (u32)h2b | ((u32)h3 << 16));
  *(uint2*)(w2 + 1024) = make_uint2(
      pack2(sv.x - bf2f(h0), sv.y - bf2f(h1)),
      pack2(sv.z - bf2f(h2b), sv.w - bf2f(h3)));
}

// ---------------- tail-only fused B phase (f32, self-contained) ----------------
DEVI void b_job(const Params& p, float* sh2, float* swb,
                const float* gi, const float* gh, const float* hold,
                float* hnew, float* wsig, float* cntd, int* dflag, int job) {
  const int tid = threadIdx.x;
  const int mt = job >> 3, nt = job & 7;
  const int r0 = mt * 8, c0 = nt * 128;
  const int gr = tid >> 5;
  const int gk = (tid & 31) * 2;
  const int wr = tid & 7;
  const int wc = (tid >> 3) * 4;
  const int row = r0 + gr;
  const float* giR = gi + row * H3_;
  const float* ghR = gh + row * H3_;
  const float* hR = hold + row * HID_;
  float* hW = hnew + row * HID_;
  float acc[4] = {0.f, 0.f, 0.f, 0.f};
  float incd = 0.f, termd = 0.f;
  const bool wh = (nt == 0);
  for (int kc = 0; kc < HID_; kc += 64) {
    float2 gxr = ld2(giR + kc + gk);
    float2 gxz = ld2(giR + 1024 + kc + gk);
    float2 gxn = ld2(giR + 2048 + kc + gk);
    float2 ghr = ld2(ghR + kc + gk);
    float2 ghz = ld2(ghR + 1024 + kc + gk);
    float2 ghn = ld2(ghR + 2048 + kc + gk);
    float2 hol = ld2(hR + kc + gk);
    float2 bri = ld2(p.bih + kc + gk);
    float2 brh = ld2(p.bhh + kc + gk);
    float2 bzi = ld2(p.bih + 1024 + kc + gk);
    float2 bzh = ld2(p.bhh + 1024 + kc + gk);
    float2 bni = ld2(p.bih + 2048 + kc + gk);
    float2 bnh = ld2(p.bhh + 2048 + kc + gk);
    float2 iw = ld2(p.incw + kc + gk);
    float2 tw = ld2(p.termw + kc + gk);
    float h2[2];
    {
      float rr = sigm(gxr.x + bri.x + ghr.x + brh.x);
      float zz = sigm(gxz.x + bzi.x + ghz.x + bzh.x);
      float nn = tanh_(gxn.x + bni.x + rr * (ghn.x + bnh.x));
      h2[0] = (1.f - zz) * nn + zz * hol.x;
      rr = sigm(gxr.y + bri.y + ghr.y + brh.y);
      zz = sigm(gxz.y + bzi.y + ghz.y + bzh.y);
      nn = tanh_(gxn.y + bni.y + rr * (ghn.y + bnh.y));
      h2[1] = (1.f - zz) * nn + zz * hol.y;
    }
    incd = fmaf(h2[0], iw.x, fmaf(h2[1], iw.y, incd));
    termd = fmaf(h2[0], tw.x, fmaf(h2[1], tw.y, termd));
    float4 wreg[8];
    #pragma unroll
    for (int it = 0; it < 8; ++it) {
      int id = tid + it * 256;
      int c = id >> 4, k4 = (id & 15) * 4;
      wreg[it] = *(const float4*)(p.ww + (c0 + c) * HID_ + kc + k4);
    }
    __syncthreads();
    sh2[gr * 68 + gk] = h2[0];
    sh2[gr * 68 + gk + 1] = h2[1];
    #pragma unroll
    for (int it = 0; it < 8; ++it) {
      int id = tid + it * 256;
      int c = id >> 4, k4 = (id & 15) * 4;
      swb[(k4 + 0) * 132 + c] = wreg[it].x;
      swb[(k4 + 1) * 132 + c] = wreg[it].y;
      swb[(k4 + 2) * 132 + c] = wreg[it].z;
      swb[(k4 + 3) * 132 + c] = wreg[it].w;
    }
    if (wh) {
      *(float2*)(hW + kc + gk) = make_float2(h2[0], h2[1]);
      *(u32*)((us_t*)(p.ws + OFF_HHI) + row * HID_ + kc + gk) = pack2(h2[0], h2[1]);
    }
    __syncthreads();
    #pragma unroll 8
    for (int kk = 0; kk < 64; ++kk) {
      float a = sh2[wr * 68 + kk];
      float4 b = *(const float4*)(swb + kk * 132 + wc);
      acc[0] = fmaf(a, b.x, acc[0]);
      acc[1] = fmaf(a, b.y, acc[1]);
      acc[2] = fmaf(a, b.z, acc[2]);
      acc[3] = fmaf(a, b.w, acc[3]);
    }
  }
  if (wh) {
    #pragma unroll
    for (int off = 16; off > 0; off >>= 1) {
      incd += __shfl_down(incd, off, 32);
      termd += __shfl_down(termd, off, 32);
    }
    if ((tid & 31) == 0) {
      float cd = sigm(incd + p.incb[0]);
      cntd[row] = cd;
      p.out[row] += cd;
      if (termd + p.termb[0] <= 0.f) atomicAnd(dflag, 0);
    }
  }
  {
    const int m = r0 + wr;
    float4 wb4 = *(const float4*)(p.wb + c0 + wc);
    float4 sv = {sigm(acc[0] + wb4.x), sigm(acc[1] + wb4.y),
                 sigm(acc[2] + wb4.z), sigm(acc[3] + wb4.w)};
    float* op = p.out + B_ + m * HW_ + c0 + wc;
    float4 ov = *(float4*)op;
    ov.x += sv.x; ov.y += sv.y; ov.z += sv.z; ov.w += sv.w;
    *(float4*)op = ov;
    *(float4*)(wsig + m * HID_ + c0 + wc) = sv;
    us_t* w2 = (us_t*)(p.ws + OFF_WSIG2) + m * 2048 + c0 + wc;
    us_t h0 = f2bf(sv.x), h1 = f2bf(sv.y), h2b = f2bf(sv.z), h3 = f2bf(sv.w);
    *(uint2*)w2 = make_uint2((u32)h0 | ((u32)h1 << 16), (u32)h2b | ((u32)h3 << 16));
    *(uint2*)(w2 + 1024) = make_uint2(
        pack2(sv.x - bf2f(h0), sv.y - bf2f(h1)),
        pack2(sv.z - bf2f(h2b), sv.w - bf2f(h3)));
  }
}

// ---- f32 double-buffered 64x64 GEMM tile (tail fallback); SB = scalar B loads ----
template <bool SB>
DEVI void gemm_db64(const float* __restrict__ A, int lda,
                    const float* __restrict__ Bw, int ldb, int K,
                    float* __restrict__ As, float* __restrict__ Bs,
                    float (&acc)[4][4]) {
  constexpr int P = 68;
  const int tid = threadIdx.x;
  const int tx = tid & 15, ty = tid >> 4;
  const int lr = tid >> 2, lk = (tid & 3) << 2;
  #pragma unroll
  for (int i = 0; i < 4; ++i)
    #pragma unroll
    for (int j = 0; j < 4; ++j) acc[i][j] = 0.f;
  auto ldb4 = [&](int k0) {
    float4 v;
    if constexpr (SB) {
      const float* q = Bw + (size_t)lr * ldb + k0 + lk;
      v.x = q[0]; v.y = q[1]; v.z = q[2]; v.w = q[3];
    } else {
      v = *(const float4*)(Bw + (size_t)lr * ldb + k0 + lk);
    }
    return v;
  };
  float4 va = *(const float4*)(A + lr * lda + lk);
  float4 vb = ldb4(0);
  As[(lk + 0) * P + lr] = va.x; As[(lk + 1) * P + lr] = va.y;
  As[(lk + 2) * P + lr] = va.z; As[(lk + 3) * P + lr] = va.w;
  Bs[(lk + 0) * P + lr] = vb.x; Bs[(lk + 1) * P + lr] = vb.y;
  Bs[(lk + 2) * P + lr] = vb.z; Bs[(lk + 3) * P + lr] = vb.w;
  __syncthreads();
  int cur = 0;
  for (int k0 = 16; k0 < K; k0 += 16) {
    va = *(const float4*)(A + lr * lda + k0 + lk);
    vb = ldb4(k0);
    const float* as = As + cur * (16 * P);
    const float* bs = Bs + cur * (16 * P);
    #pragma unroll
    for (int kk = 0; kk < 16; ++kk) {
      float a[4], b[4];
      ld4(a, as + kk * P + ty * 4);
      ld4(b, bs + kk * P + tx * 4);
      #pragma unroll
      for (int i = 0; i < 4; ++i)
        #pragma unroll
        for (int j = 0; j < 4; ++j) acc[i][j] = fmaf(a[i], b[j], acc[i][j]);
    }
    __syncthreads();
    float* asw = As + (cur ^ 1) * (16 * P);
    float* bsw = Bs + (cur ^ 1) * (16 * P);
    asw[(lk + 0) * P + lr] = va.x; asw[(lk + 1) * P + lr] = va.y;
    asw[(lk + 2) * P + lr] = va.z; asw[(lk + 3) * P + lr] = va.w;
    bsw[(lk + 0) * P + lr] = vb.x; bsw[(lk + 1) * P + lr] = vb.y;
    bsw[(lk + 2) * P + lr] = vb.z; bsw[(lk + 3) * P + lr] = vb.w;
    __syncthreads();
    cur ^= 1;
  }
  const float* as = As + cur * (16 * P);
  const float* bs = Bs + cur * (16 * P);
  #pragma unroll
  for (int kk = 0; kk < 16; ++kk) {
    float a[4], b[4];
    ld4(a, as + kk * P + ty * 4);
    ld4(b, bs + kk * P + tx * 4);
    #pragma unroll
    for (int i = 0; i < 4; ++i)
      #pragma unroll
      for (int j = 0; j < 4; ++j) acc[i][j] = fmaf(a[i], b[j], acc[i][j]);
  }
}

// ---------------- cooperative tail (steps >= start; usually exits) ----------
__global__ __launch_bounds__(NT_, 2) void tail_kernel(Params p, int start) {
  int* flags = (int*)(p.ws + OFF_FLAGS);
  if (((volatile int*)flags)[start - 1]) return;
  cg::grid_group gg = cg::this_grid();
  __shared__ __align__(16) float smem[8992];
  float* As = smem;
  float* Bs = smem + 2176;
  float* sh2 = smem;
  float* swb = smem + 544;
  float* const ws = p.ws;
  float* const gi = ws + OFF_GI;
  float* const gh = ws + OFF_GH;
  float* const wsig = ws + OFF_WSIG;
  float* const cntd = ws + OFF_CNTD;
  const float* const wihc = ws + OFF_WIHC;
  const int tid = threadIdx.x;
  const int bid = blockIdx.x;
  const int nb = gridDim.x;
  const int tx = tid & 15, ty = tid >> 4;
  const int msteps = p.max_steps[0];

  for (int step = start; step < msteps; ++step) {
    float* hcur = ws + ((step & 1) ? OFF_H1 : OFF_H0);
    float* hnxt = ws + ((step & 1) ? OFF_H0 : OFF_H1);
    for (int job = bid; job < 384; job += nb) {
      float acc[4][4];
      if (job < 192) {
        const int mt = job / 48, nt = job - mt * 48;
        gemm_db64<true>(wsig + mt * 64 * HID_, HID_,
                        p.wih + (size_t)nt * 64 * XD_ + 512, XD_, HID_, As, Bs, acc);
        #pragma unroll
        for (int i = 0; i < 4; ++i) {
          const int m = mt * 64 + ty * 4 + i;
          const float cd = cntd[m];
          float4 wc4 = *(const float4*)(wihc + nt * 64 + tx * 4);
          float* gp = gi + m * H3_ + nt * 64 + tx * 4;
          float4 g = *(float4*)gp;
          g.x += acc[i][0] + cd * wc4.x;
          g.y += acc[i][1] + cd * wc4.y;
          g.z += acc[i][2] + cd * wc4.z;
          g.w += acc[i][3] + cd * wc4.w;
          *(float4*)gp = g;
        }
      } else {
        const int j = job - 192;
        const int mt = j / 48, nt = j - mt * 48;
        gemm_db64<false>(hcur + mt * 64 * HID_, HID_,
                         p.whh + (size_t)nt * 64 * HID_, HID_, HID_, As, Bs, acc);
        #pragma unroll
        for (int i = 0; i < 4; ++i) {
          float4 v = {acc[i][0], acc[i][1], acc[i][2], acc[i][3]};
          *(float4*)(gh + (mt * 64 + ty * 4 + i) * H3_ + nt * 64 + tx * 4) = v;
        }
      }
      __syncthreads();
    }
    gg.sync();
    for (int job = bid; job < 256; job += nb)
      b_job(p, sh2, swb, gi, gh, hcur, hnxt, wsig, cntd, &flags[step], job);
    gg.sync();
    if (((volatile int*)flags)[step]) break;
  }
}

extern "C" void kernel_launch(void* const* d_in, const int* in_sizes, int n_in,
                              void* d_out, int out_size, void* d_ws, size_t ws_size,
                              hipStream_t stream) {
  (void)in_sizes; (void)n_in; (void)ws_size;
  Params prm;
  prm.grid = (const float*)d_in[0];
  prm.c1w  = (const float*)d_in[1];
  prm.c1b  = (const float*)d_in[2];
  prm.c2w  = (const float*)d_in[3];
  prm.c2b  = (const float*)d_in[4];
  prm.linw = (const float*)d_in[5];
  prm.linb = (const float*)d_in[6];
  prm.wih  = (const float*)d_in[7];
  prm.whh  = (const float*)d_in[8];
  prm.bih  = (const float*)d_in[9];
  prm.bhh  = (const float*)d_in[10];
  prm.ww   = (const float*)d_in[11];
  prm.wb   = (const float*)d_in[12];
  prm.incw = (const float*)d_in[13];
  prm.incb = (const float*)d_in[14];
  prm.termw = (const float*)d_in[15];
  prm.termb = (const float*)d_in[16];
  prm.max_steps = (const int*)d_in[17];
  prm.out = (float*)d_out;
  prm.ws = (float*)d_ws;

  hipLaunchKernelGGL(conv_kernel, dim3(B_), dim3(NT_), 0, stream, prm);
  hipLaunchKernelGGL(prep_kernel, dim3(2048), dim3(NT_), 0, stream, prm);
  hipLaunchKernelGGL(lin_mfma, dim3(256), dim3(NT_), 0, stream, prm);
  hipLaunchKernelGGL(red_kernel, dim3(512), dim3(NT_), 0, stream, prm);
  hipMemsetAsync(d_out, 0, (size_t)out_size * sizeof(float), stream);
  hipLaunchKernelGGL(a1_mfma, dim3(96), dim3(NT_), 0, stream, prm);

  constexpr int U = 3;
  hipLaunchKernelGGL(stepG_kernel, dim3(B_), dim3(NT_), 0, stream, prm, 0);
  hipLaunchKernelGGL(stepW_mfma, dim3(256), dim3(NT_), 0, stream, prm, 0);
  hipLaunchKernelGGL(stepWepi_kernel, dim3(256), dim3(NT_), 0, stream, prm, 0);
  for (int t = 1; t < U; ++t) {
    hipLaunchKernelGGL(stepA_mfma, dim3(384), dim3(NT_), 0, stream, prm, t);
    hipLaunchKernelGGL(stepG_kernel, dim3(B_), dim3(NT_), 0, stream, prm, t);
    hipLaunchKernelGGL(stepW_mfma, dim3(256), dim3(NT_), 0, stream, prm, t);
    hipLaunchKernelGGL(stepWepi_kernel, dim3(256), dim3(NT_), 0, stream, prm, t);
  }
  int start = U;
  void* args[] = {(void*)&prm, (void*)&start};
  (void)hipLaunchCooperativeKernel((const void*)tail_kernel, dim3(384), dim3(NT_),
                                   args, 0, stream);
}

// Round 6
// 138.808 us; speedup vs baseline: 5.9451x; 1.1204x over previous
//
#include <hip/hip_runtime.h>
#include <hip/hip_cooperative_groups.h>

namespace cg = cooperative_groups;

#define DEVI static __device__ __forceinline__

typedef __attribute__((ext_vector_type(8))) short s8v;    // 8 bf16 (4 VGPR)
typedef __attribute__((ext_vector_type(4))) float f32x4;
typedef unsigned short us_t;
typedef unsigned int u32;

constexpr int NT_ = 256;
constexpr int B_ = 256, HW_ = 1024, IN_ = 512, HID_ = 1024, H3_ = 3072;
constexpr int XD_ = 1537;
constexpr int FLAT_ = 16384;

// ---- workspace layout (float offsets); ws_size = 256 MiB (observed) ----
constexpr int OFF_WIHFBF = 0;                 // 3072*512 bf16
constexpr int OFF_WIHM2  = 393216;            // 3072*2048 bf16 (hi|lo)
constexpr int OFF_WHHBF  = 3538944;           // 3072*1024 bf16
constexpr int OFF_WIHC   = 5111808;           // 3072 f32
constexpr int OFF_CNTD   = 5114880;           // 256
constexpr int OFF_FLAGS  = 5115136;           // 128 ints
constexpr int OFF_FEATBF = 5115264;           // 256*512 bf16
constexpr int OFF_GI     = 5180800;           // 786432 f32
constexpr int OFF_GH     = 5967232;           // 786432 (tail-only)
constexpr int OFF_H0     = 6753664;           // 262144
constexpr int OFF_H1     = 7015808;           // 262144
constexpr int OFF_WSIG   = 7277952;           // 262144 f32 (tail path)
constexpr int OFF_HHI    = 7540096;           // 256*1024 bf16
constexpr int OFF_WSIG2  = 7671168;           // 256*2048 bf16 (hi|lo)
constexpr int OFF_C2BF   = 7933312;           // 256*16384 bf16 (dead after lin)
constexpr int OFF_LINWBF = 10030464;          // 512*16384 bf16 (dead after lin)
// aliases / extras:
constexpr int OFF_PART = OFF_GI;              // lin split-K partials (16*131072)
constexpr int OFF_PW   = OFF_C2BF;            // stepW partials 8*262144 (dead c2bf)
constexpr int OFF_WWBF = 10292608;            // 1024*1024 bf16 (inside dead linwbf)
constexpr int OFF_PA2  = 14224768;            // stepA partials 8*786432 f32 -> ends 20.5M (82MB)

struct Params {
  const float* grid;
  const float* c1w; const float* c1b;
  const float* c2w; const float* c2b;
  const float* linw; const float* linb;
  const float* wih; const float* whh;
  const float* bih; const float* bhh;
  const float* ww;  const float* wb;
  const float* incw; const float* incb;
  const float* termw; const float* termb;
  const int* max_steps;
  float* out;   // [0:256) count, [256:262400) mask [256][1024]
  float* ws;
};

DEVI float sigm(float x) { return 1.f / (1.f + __expf(-x)); }
DEVI float tanh_(float x) { return 1.f - 2.f / (__expf(2.f * x) + 1.f); }
DEVI float2 ld2(const float* p) { return *(const float2*)p; }
DEVI void ld4(float* d, const float* p) {
  float4 v = *(const float4*)p; d[0] = v.x; d[1] = v.y; d[2] = v.z; d[3] = v.w;
}
DEVI us_t f2bf(float x) {            // RNE f32->bf16
  union { float f; u32 u; } v; v.f = x;
  u32 r = v.u + 0x7FFFu + ((v.u >> 16) & 1u);
  return (us_t)(r >> 16);
}
DEVI float bf2f(us_t h) {
  union { u32 u; float f; } v; v.u = ((u32)h) << 16; return v.f;
}
DEVI u32 pack2(float a, float b) { return (u32)f2bf(a) | ((u32)f2bf(b) << 16); }

// ------- front: blocks [0,256) conv; blocks [256,2304) prep conversions -------
__global__ __launch_bounds__(NT_) void front_kernel(Params p) {
  __shared__ float smem[34 * 34 + 8 * 34 * 34];
  const int tid = threadIdx.x;
  if (blockIdx.x < 256) {
    float* s_in = smem;
    float* s_c1 = smem + 34 * 34;
    const int b = blockIdx.x;
    for (int i = tid; i < 34 * 34; i += NT_) s_in[i] = 0.f;
    for (int i = tid; i < 8 * 34 * 34; i += NT_) s_c1[i] = 0.f;
    __syncthreads();
    for (int i = tid; i < 1024; i += NT_) {
      int y = i >> 5, x = i & 31;
      s_in[(y + 1) * 34 + (x + 1)] = p.grid[b * 1024 + i];
    }
    __syncthreads();
    const int pos0 = tid * 4;
    const int y = pos0 >> 5, x0 = pos0 & 31;
    {
      float win[3][6];
      #pragma unroll
      for (int dy = 0; dy < 3; ++dy)
        #pragma unroll
        for (int c = 0; c < 6; ++c) win[dy][c] = s_in[(y + dy) * 34 + x0 + c];
      float acc[8][4];
      #pragma unroll
      for (int oc = 0; oc < 8; ++oc)
        #pragma unroll
        for (int i = 0; i < 4; ++i) acc[oc][i] = p.c1b[oc];
      #pragma unroll
      for (int oc = 0; oc < 8; ++oc)
        #pragma unroll
        for (int dy = 0; dy < 3; ++dy)
          #pragma unroll
          for (int dx = 0; dx < 3; ++dx) {
            float w = p.c1w[oc * 9 + dy * 3 + dx];
            #pragma unroll
            for (int i = 0; i < 4; ++i)
              acc[oc][i] = fmaf(w, win[dy][i + dx], acc[oc][i]);
          }
      #pragma unroll
      for (int oc = 0; oc < 8; ++oc)
        #pragma unroll
        for (int i = 0; i < 4; ++i)
          s_c1[oc * 1156 + (y + 1) * 34 + (x0 + i + 1)] = fmaxf(acc[oc][i], 0.f);
    }
    __syncthreads();
    {
      float acc[16][4];
      #pragma unroll
      for (int oc = 0; oc < 16; ++oc)
        #pragma unroll
        for (int i = 0; i < 4; ++i) acc[oc][i] = p.c2b[oc];
      for (int ic = 0; ic < 8; ++ic) {
        float win[3][6];
        #pragma unroll
        for (int dy = 0; dy < 3; ++dy)
          #pragma unroll
          for (int c = 0; c < 6; ++c)
            win[dy][c] = s_c1[ic * 1156 + (y + dy) * 34 + x0 + c];
        #pragma unroll
        for (int oc = 0; oc < 16; ++oc)
          #pragma unroll
          for (int dy = 0; dy < 3; ++dy)
            #pragma unroll
            for (int dx = 0; dx < 3; ++dx) {
              float w = p.c2w[oc * 72 + ic * 9 + dy * 3 + dx];
              #pragma unroll
              for (int i = 0; i < 4; ++i)
                acc[oc][i] = fmaf(w, win[dy][i + dx], acc[oc][i]);
            }
      }
      us_t* dst = (us_t*)(p.ws + OFF_C2BF) + b * FLAT_;
      #pragma unroll
      for (int oc = 0; oc < 16; ++oc) {
        u32 lo = pack2(fmaxf(acc[oc][0], 0.f), fmaxf(acc[oc][1], 0.f));
        u32 hi = pack2(fmaxf(acc[oc][2], 0.f), fmaxf(acc[oc][3], 0.f));
        *(uint2*)(dst + oc * 1024 + pos0) = make_uint2(lo, hi);
      }
    }
  } else {
    const int gt = (blockIdx.x - 256) * NT_ + tid;
    const int gs = 2048 * NT_;
    us_t* wihf = (us_t*)(p.ws + OFF_WIHFBF);
    us_t* wihm2 = (us_t*)(p.ws + OFF_WIHM2);
    us_t* whhbf = (us_t*)(p.ws + OFF_WHHBF);
    us_t* linwbf = (us_t*)(p.ws + OFF_LINWBF);
    float* wihc = p.ws + OFF_WIHC;
    int* flags = (int*)(p.ws + OFF_FLAGS);
    for (int i = gt; i < (IN_ * FLAT_) / 4; i += gs) {
      float4 v = *(const float4*)(p.linw + (size_t)i * 4);
      *(uint2*)(linwbf + (size_t)i * 4) = make_uint2(pack2(v.x, v.y), pack2(v.z, v.w));
    }
    for (int i = gt; i < (H3_ * HID_) / 4; i += gs) {
      float4 v = *(const float4*)(p.whh + (size_t)i * 4);
      *(uint2*)(whhbf + (size_t)i * 4) = make_uint2(pack2(v.x, v.y), pack2(v.z, v.w));
    }
    for (int i = gt; i < H3_ * IN_; i += gs) {
      int n = i >> 9, k = i & 511;
      wihf[i] = f2bf(p.wih[n * XD_ + k]);
    }
    for (int i = gt; i < H3_ * HID_; i += gs) {
      int n = i >> 10, k = i & 1023;
      float v = p.wih[n * XD_ + 512 + k];
      us_t hi = f2bf(v);
      wihm2[n * 2048 + k] = hi;
      wihm2[n * 2048 + 1024 + k] = f2bf(v - bf2f(hi));
    }
    for (int i = gt; i < H3_; i += gs) wihc[i] = p.wih[i * XD_ + 1536];
    for (int i = gt; i < 128; i += gs) flags[i] = 1;
  }
}

// ---- MFMA block: C[64][128] = sum_k A[m][k]*B[n][k], bf16 in, f32 out ----
// 256 threads = 4 waves; wave w owns 64x32; K = nc*64.
// LDS swizzle: 16B unit (r,u) -> slot r*8 + (u ^ (r&7)).
DEVI void mfma_block(const us_t* __restrict__ Ag, int lda,
                     const us_t* __restrict__ Bg, int ldb, int nc,
                     us_t* __restrict__ sA, us_t* __restrict__ sB,
                     float* __restrict__ dst, int ldd) {
  const int tid = threadIdx.x;
  const int ar = tid >> 3, au = tid & 7;
  const int sw = au ^ (ar & 7);
  const int abase = (ar * 8 + sw) * 8;
  const us_t* a0p = Ag + (size_t)ar * lda + au * 8;
  const us_t* a1p = Ag + (size_t)(ar + 32) * lda + au * 8;
  const us_t* b0p = Bg + (size_t)ar * ldb + au * 8;
  const us_t* b1p = b0p + (size_t)32 * ldb;
  const us_t* b2p = b0p + (size_t)64 * ldb;
  const us_t* b3p = b0p + (size_t)96 * ldb;
  f32x4 acc[4][2];
  #pragma unroll
  for (int f = 0; f < 4; ++f) { acc[f][0] = (f32x4)0.f; acc[f][1] = (f32x4)0.f; }
  s8v ra0 = *(const s8v*)a0p;
  s8v ra1 = *(const s8v*)a1p;
  s8v rb0 = *(const s8v*)b0p;
  s8v rb1 = *(const s8v*)b1p;
  s8v rb2 = *(const s8v*)b2p;
  s8v rb3 = *(const s8v*)b3p;
  const int w = tid >> 6;
  const int lane = tid & 63;
  const int l15 = lane & 15, l4 = lane >> 4;
  const int rsw = l15 & 7;
  int c = 0;
  for (;;) {
    __syncthreads();
    *(s8v*)(sA + abase) = ra0;
    *(s8v*)(sA + abase + 2048) = ra1;
    *(s8v*)(sB + abase) = rb0;
    *(s8v*)(sB + abase + 2048) = rb1;
    *(s8v*)(sB + abase + 4096) = rb2;
    *(s8v*)(sB + abase + 6144) = rb3;
    ++c;
    if (c < nc) {
      const int ko = c * 64;
      ra0 = *(const s8v*)(a0p + ko);
      ra1 = *(const s8v*)(a1p + ko);
      rb0 = *(const s8v*)(b0p + ko);
      rb1 = *(const s8v*)(b1p + ko);
      rb2 = *(const s8v*)(b2p + ko);
      rb3 = *(const s8v*)(b3p + ko);
    }
    __syncthreads();
    #pragma unroll
    for (int kk = 0; kk < 2; ++kk) {
      const int uoff = ((kk * 4 + l4) ^ rsw) * 8;
      s8v bA = *(const s8v*)(sB + (w * 32 + l15) * 64 + uoff);
      s8v bB = *(const s8v*)(sB + (w * 32 + 16 + l15) * 64 + uoff);
      #pragma unroll
      for (int f = 0; f < 4; ++f) {
        s8v a = *(const s8v*)(sA + (f * 16 + l15) * 64 + uoff);
        acc[f][0] = __builtin_amdgcn_mfma_f32_16x16x32_bf16(a, bA, acc[f][0], 0, 0, 0);
        acc[f][1] = __builtin_amdgcn_mfma_f32_16x16x32_bf16(a, bB, acc[f][1], 0, 0, 0);
      }
    }
    if (c >= nc) break;
  }
  #pragma unroll
  for (int f = 0; f < 4; ++f)
    #pragma unroll
    for (int g = 0; g < 2; ++g) {
      float* dp = dst + (size_t)(f * 16 + l4 * 4) * ldd + w * 32 + g * 16 + l15;
      #pragma unroll
      for (int j = 0; j < 4; ++j) dp[(size_t)j * ldd] = acc[f][g][j];
    }
}

// ---------------- linear: part[ks] = c2f_bf @ linw_bf^T ----------------
__global__ __launch_bounds__(NT_) void lin_mfma(Params p) {
  __shared__ us_t sm[12288];
  const int b = blockIdx.x;                // 256 = 16ks x 4mt x 4nt
  const int ks = b & 15, t = b >> 4;
  const int mt = t >> 2, nt = t & 3;
  const us_t* A = (us_t*)(p.ws + OFF_C2BF) + (size_t)mt * 64 * FLAT_ + ks * 1024;
  const us_t* B = (us_t*)(p.ws + OFF_LINWBF) + (size_t)nt * 128 * FLAT_ + ks * 1024;
  float* dst = p.ws + OFF_PART + ks * (B_ * IN_) + mt * 64 * IN_ + nt * 128;
  mfma_block(A, FLAT_, B, FLAT_, 16, sm, sm + 4096, dst, IN_);
}

// ------------- reduce split-K -> feat bf16; also convert ww -> bf16 -------------
__global__ __launch_bounds__(NT_) void red_kernel(Params p) {
  const int gt = blockIdx.x * NT_ + threadIdx.x;   // 512 blocks, 131072 threads
  {
    const int o = gt & (IN_ - 1);
    const float* part = p.ws + OFF_PART;
    float s = p.linb[o];
    #pragma unroll
    for (int ks = 0; ks < 16; ++ks) s += part[ks * (B_ * IN_) + gt];
    ((us_t*)(p.ws + OFF_FEATBF))[gt] = f2bf(s);
  }
  us_t* wwbf = (us_t*)(p.ws + OFF_WWBF);
  #pragma unroll
  for (int r = 0; r < 2; ++r) {
    const int j = gt + r * 131072;                 // 262144 float4 units total
    float4 v = *(const float4*)(p.ww + (size_t)j * 4);
    *(uint2*)(wwbf + (size_t)j * 4) = make_uint2(pack2(v.x, v.y), pack2(v.z, v.w));
  }
}

// ---------------- gi_base = feat @ wihf^T ----------------
__global__ __launch_bounds__(NT_) void a1_mfma(Params p) {
  __shared__ us_t sm[12288];
  const int b = blockIdx.x;                // 96 = 4mt*24nt
  const int mt = b / 24, nt = b - mt * 24;
  const us_t* A = (us_t*)(p.ws + OFF_FEATBF) + (size_t)mt * 64 * IN_;
  const us_t* B = (us_t*)(p.ws + OFF_WIHFBF) + (size_t)nt * 128 * IN_;
  float* dst = p.ws + OFF_GI + (size_t)mt * 64 * H3_ + nt * 128;
  mfma_block(A, IN_, B, IN_, 8, sm, sm + 4096, dst, H3_);
}

// ------- A phase MFMA, split-K=2: 768 = 576 G1(3 terms x 2ks) + 192 G2(2ks) -------
__global__ __launch_bounds__(NT_) void stepA_mfma(Params p, int step) {
  if (((volatile int*)(p.ws + OFF_FLAGS))[step - 1]) return;
  __shared__ us_t sm[12288];
  const int b = blockIdx.x;
  if (b < 576) {
    const int term = b / 192;
    const int r = b - term * 192;
    const int ks = r / 96;
    const int t = r - ks * 96;
    const int mt = t / 24, nt = t - mt * 24;
    const us_t* A = (us_t*)(p.ws + OFF_WSIG2) + (size_t)mt * 64 * 2048 +
                    (term == 1 ? 1024 : 0) + ks * 512;
    const us_t* B = (us_t*)(p.ws + OFF_WIHM2) + (size_t)nt * 128 * 2048 +
                    (term == 2 ? 1024 : 0) + ks * 512;
    float* dst = p.ws + OFF_PA2 + (size_t)(term * 2 + ks) * 786432 +
                 (size_t)mt * 64 * H3_ + nt * 128;
    mfma_block(A, 2048, B, 2048, 8, sm, sm + 4096, dst, H3_);
  } else {
    const int r = b - 576;
    const int ks = r / 96;
    const int t = r - ks * 96;
    const int mt = t / 24, nt = t - mt * 24;
    const us_t* A = (us_t*)(p.ws + OFF_HHI) + (size_t)mt * 64 * HID_ + ks * 512;
    const us_t* B = (us_t*)(p.ws + OFF_WHHBF) + (size_t)nt * 128 * HID_ + ks * 512;
    float* dst = p.ws + OFF_PA2 + (size_t)(6 + ks) * 786432 +
                 (size_t)mt * 64 * H3_ + nt * 128;
    mfma_block(A, HID_, B, HID_, 8, sm, sm + 4096, dst, H3_);
  }
}

// ---- stepG: fold 8 A-partials into gi/gh, gates once per row, dots, count/flag ----
__global__ __launch_bounds__(NT_) void stepG_kernel(Params p, int step) {
  int* flags = (int*)(p.ws + OFF_FLAGS);
  if (step > 0 && ((volatile int*)flags)[step - 1]) return;
  __shared__ float sred[8];
  const int row = blockIdx.x;
  const int tid = threadIdx.x;
  const size_t base = (size_t)row * H3_;
  float* const gi = p.ws + OFF_GI + base;
  const float* const pA = p.ws + OFF_PA2;
  const float* const wihc = p.ws + OFF_WIHC;
  const float* hold = p.ws + ((step & 1) ? OFF_H1 : OFF_H0) + (size_t)row * HID_;
  float* hnew = p.ws + ((step & 1) ? OFF_H0 : OFF_H1) + (size_t)row * HID_;
  us_t* hhi = (us_t*)(p.ws + OFF_HHI) + (size_t)row * HID_;
  const float cd = (step > 0) ? (p.ws + OFF_CNTD)[row] : 0.f;
  float incd = 0.f, termd = 0.f;
  #pragma unroll
  for (int q = 0; q < 4; ++q) {
    const int c = tid + q * NT_;
    float gr_ = gi[c], gz_ = gi[1024 + c], gn_ = gi[2048 + c];
    float hr_ = 0.f, hz_ = 0.f, hn_ = 0.f, hv = 0.f;
    if (step > 0) {
      #pragma unroll
      for (int t6 = 0; t6 < 6; ++t6) {
        const float* pp = pA + (size_t)t6 * 786432 + base;
        gr_ += pp[c]; gz_ += pp[1024 + c]; gn_ += pp[2048 + c];
      }
      gr_ += cd * wihc[c];
      gz_ += cd * wihc[1024 + c];
      gn_ += cd * wihc[2048 + c];
      const float* q6 = pA + (size_t)6 * 786432 + base;
      const float* q7 = pA + (size_t)7 * 786432 + base;
      hr_ = q6[c] + q7[c];
      hz_ = q6[1024 + c] + q7[1024 + c];
      hn_ = q6[2048 + c] + q7[2048 + c];
      gi[c] = gr_; gi[1024 + c] = gz_; gi[2048 + c] = gn_;   // materialize for tail
      hv = hold[c];
    }
    float rr = sigm(gr_ + p.bih[c] + hr_ + p.bhh[c]);
    float zz = sigm(gz_ + p.bih[1024 + c] + hz_ + p.bhh[1024 + c]);
    float nn = tanh_(gn_ + p.bih[2048 + c] + rr * (hn_ + p.bhh[2048 + c]));
    float h2 = (1.f - zz) * nn + zz * hv;
    hnew[c] = h2;
    hhi[c] = f2bf(h2);
    incd = fmaf(h2, p.incw[c], incd);
    termd = fmaf(h2, p.termw[c], termd);
  }
  #pragma unroll
  for (int off = 32; off > 0; off >>= 1) {
    incd += __shfl_down(incd, off);
    termd += __shfl_down(termd, off);
  }
  if ((tid & 63) == 0) { sred[tid >> 6] = incd; sred[4 + (tid >> 6)] = termd; }
  __syncthreads();
  if (tid == 0) {
    float it = sred[0] + sred[1] + sred[2] + sred[3];
    float tt = sred[4] + sred[5] + sred[6] + sred[7];
    float cdn = sigm(it + p.incb[0]);
    (p.ws + OFF_CNTD)[row] = cdn;
    if (step == 0) p.out[row] = cdn;     // step0 writes (d_out not pre-zeroed)
    else p.out[row] += cdn;
    if (tt + p.termb[0] <= 0.f) atomicAnd(&flags[step], 0);
  }
}

// ---------------- stepW: write-GEMM partials via MFMA, split-K=8 ----------------
__global__ __launch_bounds__(NT_) void stepW_mfma(Params p, int step) {
  if (step > 0 && ((volatile int*)(p.ws + OFF_FLAGS))[step - 1]) return;
  __shared__ us_t sm[12288];
  const int b = blockIdx.x;           // 256 = 8ks x 4mt x 8nt
  const int ks = b & 7, t = b >> 3;
  const int mt = t >> 3, nt = t & 7;
  const us_t* A = (us_t*)(p.ws + OFF_HHI) + (size_t)mt * 64 * HID_ + ks * 128;
  const us_t* B = (us_t*)(p.ws + OFF_WWBF) + (size_t)nt * 128 * HID_ + ks * 128;
  float* dst = p.ws + OFF_PW + ks * (B_ * HW_) + (size_t)mt * 64 * HW_ + nt * 128;
  mfma_block(A, HID_, B, HID_, 2, sm, sm + 4096, dst, HW_);
}

// ------- stepWepi: reduce partials, sigmoid, mask write/accum, wsig/wsig2 emit -------
__global__ __launch_bounds__(NT_) void stepWepi_kernel(Params p, int step) {
  if (step > 0 && ((volatile int*)(p.ws + OFF_FLAGS))[step - 1]) return;
  const int i = (blockIdx.x * NT_ + threadIdx.x) * 4;   // 256 blocks exact
  const int m = i >> 10, n = i & 1023;
  const float* pW = p.ws + OFF_PW;
  float4 s = *(const float4*)(p.wb + n);
  #pragma unroll
  for (int ks = 0; ks < 8; ++ks) {
    float4 v = *(const float4*)(pW + ks * (B_ * HW_) + i);
    s.x += v.x; s.y += v.y; s.z += v.z; s.w += v.w;
  }
  float4 sv = {sigm(s.x), sigm(s.y), sigm(s.z), sigm(s.w)};
  float* op = p.out + B_ + i;
  if (step == 0) {
    *(float4*)op = sv;                 // step0 writes (d_out not pre-zeroed)
  } else {
    float4 ov = *(float4*)op;
    ov.x += sv.x; ov.y += sv.y; ov.z += sv.z; ov.w += sv.w;
    *(float4*)op = ov;
  }
  *(float4*)(p.ws + OFF_WSIG + i) = sv;
  us_t* w2 = (us_t*)(p.ws + OFF_WSIG2) + (size_t)m * 2048 + n;
  us_t h0 = f2bf(sv.x), h1 = f2bf(sv.y), h2b = f2bf(sv.z), h3 = f2bf(sv.w);
  *(uint2*)w2 = make_uint2((u32)h0 | ((u32)h1 << 16), (u32)h2b | ((u32)h3 << 16));
  *(uint2*)(w2 + 1024) = make_uint2(
      pack2(sv.x - bf2f(h0), sv.y - bf2f(h1)),
      pack2(sv.z - bf2f(h2b), sv.w - bf2f(h3)));
}

// ---------------- tail-only fused B phase (f32, self-contained) ----------------
DEVI void b_job(const Params& p, float* sh2, float* swb,
                const float* gi, const float* gh, const float* hold,
                float* hnew, float* wsig, float* cntd, int* dflag, int job) {
  const int tid = threadIdx.x;
  const int mt = job >> 3, nt = job & 7;
  const int r0 = mt * 8, c0 = nt * 128;
  const int gr = tid >> 5;
  const int gk = (tid & 31) * 2;
  const int wr = tid & 7;
  const int wc = (tid >> 3) * 4;
  const int row = r0 + gr;
  const float* giR = gi + row * H3_;
  const float* ghR = gh + row * H3_;
  const float* hR = hold + row * HID_;
  float* hW = hnew + row * HID_;
  float acc[4] = {0.f, 0.f, 0.f, 0.f};
  float incd = 0.f, termd = 0.f;
  const bool wh = (nt == 0);
  for (int kc = 0; kc < HID_; kc += 64) {
    float2 gxr = ld2(giR + kc + gk);
    float2 gxz = ld2(giR + 1024 + kc + gk);
    float2 gxn = ld2(giR + 2048 + kc + gk);
    float2 ghr = ld2(ghR + kc + gk);
    float2 ghz = ld2(ghR + 1024 + kc + gk);
    float2 ghn = ld2(ghR + 2048 + kc + gk);
    float2 hol = ld2(hR + kc + gk);
    float2 bri = ld2(p.bih + kc + gk);
    float2 brh = ld2(p.bhh + kc + gk);
    float2 bzi = ld2(p.bih + 1024 + kc + gk);
    float2 bzh = ld2(p.bhh + 1024 + kc + gk);
    float2 bni = ld2(p.bih + 2048 + kc + gk);
    float2 bnh = ld2(p.bhh + 2048 + kc + gk);
    float2 iw = ld2(p.incw + kc + gk);
    float2 tw = ld2(p.termw + kc + gk);
    float h2[2];
    {
      float rr = sigm(gxr.x + bri.x + ghr.x + brh.x);
      float zz = sigm(gxz.x + bzi.x + ghz.x + bzh.x);
      float nn = tanh_(gxn.x + bni.x + rr * (ghn.x + bnh.x));
      h2[0] = (1.f - zz) * nn + zz * hol.x;
      rr = sigm(gxr.y + bri.y + ghr.y + brh.y);
      zz = sigm(gxz.y + bzi.y + ghz.y + bzh.y);
      nn = tanh_(gxn.y + bni.y + rr * (ghn.y + bnh.y));
      h2[1] = (1.f - zz) * nn + zz * hol.y;
    }
    incd = fmaf(h2[0], iw.x, fmaf(h2[1], iw.y, incd));
    termd = fmaf(h2[0], tw.x, fmaf(h2[1], tw.y, termd));
    float4 wreg[8];
    #pragma unroll
    for (int it = 0; it < 8; ++it) {
      int id = tid + it * 256;
      int c = id >> 4, k4 = (id & 15) * 4;
      wreg[it] = *(const float4*)(p.ww + (c0 + c) * HID_ + kc + k4);
    }
    __syncthreads();
    sh2[gr * 68 + gk] = h2[0];
    sh2[gr * 68 + gk + 1] = h2[1];
    #pragma unroll
    for (int it = 0; it < 8; ++it) {
      int id = tid + it * 256;
      int c = id >> 4, k4 = (id & 15) * 4;
      swb[(k4 + 0) * 132 + c] = wreg[it].x;
      swb[(k4 + 1) * 132 + c] = wreg[it].y;
      swb[(k4 + 2) * 132 + c] = wreg[it].z;
      swb[(k4 + 3) * 132 + c] = wreg[it].w;
    }
    if (wh) {
      *(float2*)(hW + kc + gk) = make_float2(h2[0], h2[1]);
      *(u32*)((us_t*)(p.ws + OFF_HHI) + row * HID_ + kc + gk) = pack2(h2[0], h2[1]);
    }
    __syncthreads();
    #pragma unroll 8
    for (int kk = 0; kk < 64; ++kk) {
      float a = sh2[wr * 68 + kk];
      float4 b = *(const float4*)(swb + kk * 132 + wc);
      acc[0] = fmaf(a, b.x, acc[0]);
      acc[1] = fmaf(a, b.y, acc[1]);
      acc[2] = fmaf(a, b.z, acc[2]);
      acc[3] = fmaf(a, b.w, acc[3]);
    }
  }
  if (wh) {
    #pragma unroll
    for (int off = 16; off > 0; off >>= 1) {
      incd += __shfl_down(incd, off, 32);
      termd += __shfl_down(termd, off, 32);
    }
    if ((tid & 31) == 0) {
      float cd = sigm(incd + p.incb[0]);
      cntd[row] = cd;
      p.out[row] += cd;
      if (termd + p.termb[0] <= 0.f) atomicAnd(dflag, 0);
    }
  }
  {
    const int m = r0 + wr;
    float4 wb4 = *(const float4*)(p.wb + c0 + wc);
    float4 sv = {sigm(acc[0] + wb4.x), sigm(acc[1] + wb4.y),
                 sigm(acc[2] + wb4.z), sigm(acc[3] + wb4.w)};
    float* op = p.out + B_ + m * HW_ + c0 + wc;
    float4 ov = *(float4*)op;
    ov.x += sv.x; ov.y += sv.y; ov.z += sv.z; ov.w += sv.w;
    *(float4*)op = ov;
    *(float4*)(wsig + m * HID_ + c0 + wc) = sv;
    us_t* w2 = (us_t*)(p.ws + OFF_WSIG2) + m * 2048 + c0 + wc;
    us_t h0 = f2bf(sv.x), h1 = f2bf(sv.y), h2b = f2bf(sv.z), h3 = f2bf(sv.w);
    *(uint2*)w2 = make_uint2((u32)h0 | ((u32)h1 << 16), (u32)h2b | ((u32)h3 << 16));
    *(uint2*)(w2 + 1024) = make_uint2(
        pack2(sv.x - bf2f(h0), sv.y - bf2f(h1)),
        pack2(sv.z - bf2f(h2b), sv.w - bf2f(h3)));
  }
}

// ---- f32 double-buffered 64x64 GEMM tile (tail fallback); SB = scalar B loads ----
template <bool SB>
DEVI void gemm_db64(const float* __restrict__ A, int lda,
                    const float* __restrict__ Bw, int ldb, int K,
                    float* __restrict__ As, float* __restrict__ Bs,
                    float (&acc)[4][4]) {
  constexpr int P = 68;
  const int tid = threadIdx.x;
  const int tx = tid & 15, ty = tid >> 4;
  const int lr = tid >> 2, lk = (tid & 3) << 2;
  #pragma unroll
  for (int i = 0; i < 4; ++i)
    #pragma unroll
    for (int j = 0; j < 4; ++j) acc[i][j] = 0.f;
  auto ldb4 = [&](int k0) {
    float4 v;
    if constexpr (SB) {
      const float* q = Bw + (size_t)lr * ldb + k0 + lk;
      v.x = q[0]; v.y = q[1]; v.z = q[2]; v.w = q[3];
    } else {
      v = *(const float4*)(Bw + (size_t)lr * ldb + k0 + lk);
    }
    return v;
  };
  float4 va = *(const float4*)(A + lr * lda + lk);
  float4 vb = ldb4(0);
  As[(lk + 0) * P + lr] = va.x; As[(lk + 1) * P + lr] = va.y;
  As[(lk + 2) * P + lr] = va.z; As[(lk + 3) * P + lr] = va.w;
  Bs[(lk + 0) * P + lr] = vb.x; Bs[(lk + 1) * P + lr] = vb.y;
  Bs[(lk + 2) * P + lr] = vb.z; Bs[(lk + 3) * P + lr] = vb.w;
  __syncthreads();
  int cur = 0;
  for (int k0 = 16; k0 < K; k0 += 16) {
    va = *(const float4*)(A + lr * lda + k0 + lk);
    vb = ldb4(k0);
    const float* as = As + cur * (16 * P);
    const float* bs = Bs + cur * (16 * P);
    #pragma unroll
    for (int kk = 0; kk < 16; ++kk) {
      float a[4], b[4];
      ld4(a, as + kk * P + ty * 4);
      ld4(b, bs + kk * P + tx * 4);
      #pragma unroll
      for (int i = 0; i < 4; ++i)
        #pragma unroll
        for (int j = 0; j < 4; ++j) acc[i][j] = fmaf(a[i], b[j], acc[i][j]);
    }
    __syncthreads();
    float* asw = As + (cur ^ 1) * (16 * P);
    float* bsw = Bs + (cur ^ 1) * (16 * P);
    asw[(lk + 0) * P + lr] = va.x; asw[(lk + 1) * P + lr] = va.y;
    asw[(lk + 2) * P + lr] = va.z; asw[(lk + 3) * P + lr] = va.w;
    bsw[(lk + 0) * P + lr] = vb.x; bsw[(lk + 1) * P + lr] = vb.y;
    bsw[(lk + 2) * P + lr] = vb.z; bsw[(lk + 3) * P + lr] = vb.w;
    __syncthreads();
    cur ^= 1;
  }
  const float* as = As + cur * (16 * P);
  const float* bs = Bs + cur * (16 * P);
  #pragma unroll
  for (int kk = 0; kk < 16; ++kk) {
    float a[4], b[4];
    ld4(a, as + kk * P + ty * 4);
    ld4(b, bs + kk * P + tx * 4);
    #pragma unroll
    for (int i = 0; i < 4; ++i)
      #pragma unroll
      for (int j = 0; j < 4; ++j) acc[i][j] = fmaf(a[i], b[j], acc[i][j]);
  }
}

// ---------------- cooperative tail (steps >= start; usually exits) ----------
__global__ __launch_bounds__(NT_, 2) void tail_kernel(Params p, int start) {
  int* flags = (int*)(p.ws + OFF_FLAGS);
  if (((volatile int*)flags)[start - 1]) return;
  cg::grid_group gg = cg::this_grid();
  __shared__ __align__(16) float smem[8992];
  float* As = smem;
  float* Bs = smem + 2176;
  float* sh2 = smem;
  float* swb = smem + 544;
  float* const ws = p.ws;
  float* const gi = ws + OFF_GI;
  float* const gh = ws + OFF_GH;
  float* const wsig = ws + OFF_WSIG;
  float* const cntd = ws + OFF_CNTD;
  const float* const wihc = ws + OFF_WIHC;
  const int tid = threadIdx.x;
  const int bid = blockIdx.x;
  const int nb = gridDim.x;
  const int tx = tid & 15, ty = tid >> 4;
  const int msteps = p.max_steps[0];

  for (int step = start; step < msteps; ++step) {
    float* hcur = ws + ((step & 1) ? OFF_H1 : OFF_H0);
    float* hnxt = ws + ((step & 1) ? OFF_H0 : OFF_H1);
    for (int job = bid; job < 384; job += nb) {
      float acc[4][4];
      if (job < 192) {
        const int mt = job / 48, nt = job - mt * 48;
        gemm_db64<true>(wsig + mt * 64 * HID_, HID_,
                        p.wih + (size_t)nt * 64 * XD_ + 512, XD_, HID_, As, Bs, acc);
        #pragma unroll
        for (int i = 0; i < 4; ++i) {
          const int m = mt * 64 + ty * 4 + i;
          const float cd = cntd[m];
          float4 wc4 = *(const float4*)(wihc + nt * 64 + tx * 4);
          float* gp = gi + m * H3_ + nt * 64 + tx * 4;
          float4 g = *(float4*)gp;
          g.x += acc[i][0] + cd * wc4.x;
          g.y += acc[i][1] + cd * wc4.y;
          g.z += acc[i][2] + cd * wc4.z;
          g.w += acc[i][3] + cd * wc4.w;
          *(float4*)gp = g;
        }
      } else {
        const int j = job - 192;
        const int mt = j / 48, nt = j - mt * 48;
        gemm_db64<false>(hcur + mt * 64 * HID_, HID_,
                         p.whh + (size_t)nt * 64 * HID_, HID_, HID_, As, Bs, acc);
        #pragma unroll
        for (int i = 0; i < 4; ++i) {
          float4 v = {acc[i][0], acc[i][1], acc[i][2], acc[i][3]};
          *(float4*)(gh + (mt * 64 + ty * 4 + i) * H3_ + nt * 64 + tx * 4) = v;
        }
      }
      __syncthreads();
    }
    gg.sync();
    for (int job = bid; job < 256; job += nb)
      b_job(p, sh2, swb, gi, gh, hcur, hnxt, wsig, cntd, &flags[step], job);
    gg.sync();
    if (((volatile int*)flags)[step]) break;
  }
}

extern "C" void kernel_launch(void* const* d_in, const int* in_sizes, int n_in,
                              void* d_out, int out_size, void* d_ws, size_t ws_size,
                              hipStream_t stream) {
  (void)in_sizes; (void)n_in; (void)out_size; (void)ws_size;
  Params prm;
  prm.grid = (const float*)d_in[0];
  prm.c1w  = (const float*)d_in[1];
  prm.c1b  = (const float*)d_in[2];
  prm.c2w  = (const float*)d_in[3];
  prm.c2b  = (const float*)d_in[4];
  prm.linw = (const float*)d_in[5];
  prm.linb = (const float*)d_in[6];
  prm.wih  = (const float*)d_in[7];
  prm.whh  = (const float*)d_in[8];
  prm.bih  = (const float*)d_in[9];
  prm.bhh  = (const float*)d_in[10];
  prm.ww   = (const float*)d_in[11];
  prm.wb   = (const float*)d_in[12];
  prm.incw = (const float*)d_in[13];
  prm.incb = (const float*)d_in[14];
  prm.termw = (const float*)d_in[15];
  prm.termb = (const float*)d_in[16];
  prm.max_steps = (const int*)d_in[17];
  prm.out = (float*)d_out;
  prm.ws = (float*)d_ws;

  hipLaunchKernelGGL(front_kernel, dim3(2304), dim3(NT_), 0, stream, prm);
  hipLaunchKernelGGL(lin_mfma, dim3(256), dim3(NT_), 0, stream, prm);
  hipLaunchKernelGGL(red_kernel, dim3(512), dim3(NT_), 0, stream, prm);
  hipLaunchKernelGGL(a1_mfma, dim3(96), dim3(NT_), 0, stream, prm);

  constexpr int U = 2;   // unrolled steps; data terminates at step 1
  hipLaunchKernelGGL(stepG_kernel, dim3(B_), dim3(NT_), 0, stream, prm, 0);
  hipLaunchKernelGGL(stepW_mfma, dim3(256), dim3(NT_), 0, stream, prm, 0);
  hipLaunchKernelGGL(stepWepi_kernel, dim3(256), dim3(NT_), 0, stream, prm, 0);
  for (int t = 1; t < U; ++t) {
    hipLaunchKernelGGL(stepA_mfma, dim3(768), dim3(NT_), 0, stream, prm, t);
    hipLaunchKernelGGL(stepG_kernel, dim3(B_), dim3(NT_), 0, stream, prm, t);
    hipLaunchKernelGGL(stepW_mfma, dim3(256), dim3(NT_), 0, stream, prm, t);
    hipLaunchKernelGGL(stepWepi_kernel, dim3(256), dim3(NT_), 0, stream, prm, t);
  }
  int start = U;
  void* args[] = {(void*)&prm, (void*)&start};
  (void)hipLaunchCooperativeKernel((const void*)tail_kernel, dim3(384), dim3(NT_),
                                   args, 0, stream);
}